// Round 1
// baseline (599.674 us; speedup 1.0000x reference)
//
#include <hip/hip_runtime.h>
#include <hip/hip_bf16.h>

typedef __bf16 bf16_t;
typedef __bf16 bf16x8 __attribute__((ext_vector_type(8)));
typedef __bf16 bf16x4 __attribute__((ext_vector_type(4)));
typedef float f32x4 __attribute__((ext_vector_type(4)));

#define T_TOK 8192
#define E_DIM 2048
#define NHEAD 32
#define DHEAD 64
#define SEQLEN 1024
#define NSEQ 8

// ---------------- fp32 -> bf16 conversion (vectorized, grid-stride) --------
__global__ void cvt_f32_bf16(const float* __restrict__ in, bf16_t* __restrict__ out, int n4) {
    int idx = blockIdx.x * blockDim.x + threadIdx.x;
    int stride = gridDim.x * blockDim.x;
    for (int i = idx; i < n4; i += stride) {
        const float4 v = reinterpret_cast<const float4*>(in)[i];
        bf16x4 o;
        o[0] = (bf16_t)v.x; o[1] = (bf16_t)v.y; o[2] = (bf16_t)v.z; o[3] = (bf16_t)v.w;
        reinterpret_cast<bf16x4*>(out)[i] = o;
    }
}

// ---------------- GEMM: C[M,N] = A[M,K] * B[N,K]^T + bias ------------------
// 128x128 tile, BK=32, 4 waves (each 64x64), global_load_lds width 16.
template<bool OUT_BF16>
__global__ __launch_bounds__(256, 2)
void gemm_bt(const bf16_t* __restrict__ A, const bf16_t* __restrict__ B,
             const float* __restrict__ bias, void* __restrict__ Cout,
             int M, int N, int K) {
    __shared__ alignas(16) bf16_t aT[128 * 32];
    __shared__ alignas(16) bf16_t bT[128 * 32];
    const int tid = threadIdx.x;
    const int w = tid >> 6, l = tid & 63;
    const int bm = blockIdx.x, bn = blockIdx.y;
    const int wr = (w >> 1) * 64, wc = (w & 1) * 64;
    const int rowf = l & 15, kg = (l >> 4) * 8;

    f32x4 acc[4][4] = {};

    const int srow = l >> 2;        // 0..15 within 16-row chunk
    const int scol = (l & 3) * 8;   // element offset within 32-elem row
    const bf16_t* aBase = A + (size_t)(bm * 128) * K;
    const bf16_t* bBase = B + (size_t)(bn * 128) * K;

    for (int k0 = 0; k0 < K; k0 += 32) {
        __syncthreads();
#pragma unroll
        for (int c = 0; c < 2; ++c) {
            const int row = (w * 2 + c) * 16 + srow;
            __builtin_amdgcn_global_load_lds(
                (const __attribute__((address_space(1))) void*)(aBase + (size_t)row * K + k0 + scol),
                (__attribute__((address_space(3))) void*)(aT + (w * 2 + c) * 512), 16, 0, 0);
            __builtin_amdgcn_global_load_lds(
                (const __attribute__((address_space(1))) void*)(bBase + (size_t)row * K + k0 + scol),
                (__attribute__((address_space(3))) void*)(bT + (w * 2 + c) * 512), 16, 0, 0);
        }
        __syncthreads();

        bf16x8 af[4], bfr[4];
#pragma unroll
        for (int i = 0; i < 4; ++i)
            af[i] = *reinterpret_cast<const bf16x8*>(aT + (wr + i * 16 + rowf) * 32 + kg);
#pragma unroll
        for (int j = 0; j < 4; ++j)
            bfr[j] = *reinterpret_cast<const bf16x8*>(bT + (wc + j * 16 + rowf) * 32 + kg);
#pragma unroll
        for (int i = 0; i < 4; ++i)
#pragma unroll
            for (int j = 0; j < 4; ++j)
                acc[i][j] = __builtin_amdgcn_mfma_f32_16x16x32_bf16(af[i], bfr[j], acc[i][j], 0, 0, 0);
    }

    // epilogue: C[row=(l>>4)*4+j][col=l&15] per 16x16 fragment
    const int r0 = bm * 128 + wr + (l >> 4) * 4;
    const int c0 = bn * 128 + wc + (l & 15);
#pragma unroll
    for (int jf = 0; jf < 4; ++jf) {
        const int col = c0 + jf * 16;
        const float bb = bias[col];
#pragma unroll
        for (int i = 0; i < 4; ++i) {
#pragma unroll
            for (int j = 0; j < 4; ++j) {
                const int row = r0 + i * 16 + j;
                const float v = acc[i][jf][j] + bb;
                if (OUT_BF16)
                    ((bf16_t*)Cout)[(size_t)row * N + col] = (bf16_t)v;
                else
                    ((float*)Cout)[(size_t)row * N + col] = v;
            }
        }
    }
}

// ---------------- Flash attention (causal, per (seq, head, qtile)) ---------
// Q-tile 64 rows, K-tile 64 rows, D=64. 4 waves; wave w owns q rows [w*16,w*16+16).
__global__ __launch_bounds__(256, 2)
void attn_fwd(const bf16_t* __restrict__ Qg, const bf16_t* __restrict__ Kg,
              const bf16_t* __restrict__ Vg, bf16_t* __restrict__ Og) {
    const int qt = blockIdx.x;   // 0..15
    const int h  = blockIdx.y;   // 0..31
    const int sq = blockIdx.z;   // 0..7
    const int tid = threadIdx.x, w = tid >> 6, l = tid & 63;
    const int lr = l & 15, lg = l >> 4;

    __shared__ alignas(16) bf16_t Kt[64 * 72];      // [k][d], stride 72
    __shared__ alignas(16) bf16_t Vt[64 * 72];      // [d][k], stride 72 (transposed)
    __shared__ alignas(16) bf16_t Pl[4][16 * 72];   // per-wave P [q][k], stride 72

    // Q fragments held in registers (A-operand layout: row=l&15, k=(l>>4)*8..)
    const int qrow_l = qt * 64 + w * 16 + lr;  // q row within seq
    const bf16_t* qp = Qg + (size_t)(sq * SEQLEN + qrow_l) * E_DIM + h * 64 + lg * 8;
    const bf16x8 qa0 = *reinterpret_cast<const bf16x8*>(qp);
    const bf16x8 qa1 = *reinterpret_cast<const bf16x8*>(qp + 32);

    f32x4 o[4] = {};
    float mr[4], ls[4];
#pragma unroll
    for (int j = 0; j < 4; ++j) { mr[j] = -3.0e38f; ls[j] = 0.f; }

    const int srow = tid >> 2;         // 0..63
    const int scol = (tid & 3) * 16;   // 0,16,32,48
    const size_t kvBase = (size_t)(sq * SEQLEN) * E_DIM + h * 64;

    for (int kt = 0; kt <= qt; ++kt) {
        __syncthreads();
        {   // stage K (row-major) and V (transposed) into LDS
            const bf16_t* kp = Kg + kvBase + (size_t)(kt * 64 + srow) * E_DIM + scol;
            *reinterpret_cast<bf16x8*>(Kt + srow * 72 + scol)     = *reinterpret_cast<const bf16x8*>(kp);
            *reinterpret_cast<bf16x8*>(Kt + srow * 72 + scol + 8) = *reinterpret_cast<const bf16x8*>(kp + 8);
            const bf16_t* vp = Vg + kvBase + (size_t)(kt * 64 + srow) * E_DIM + scol;
            const bf16x8 v0 = *reinterpret_cast<const bf16x8*>(vp);
            const bf16x8 v1 = *reinterpret_cast<const bf16x8*>(vp + 8);
#pragma unroll
            for (int t = 0; t < 8; ++t) Vt[(scol + t) * 72 + srow] = v0[t];
#pragma unroll
            for (int t = 0; t < 8; ++t) Vt[(scol + 8 + t) * 72 + srow] = v1[t];
        }
        __syncthreads();

        // S = Q * K^T  (per wave: 16 q-rows x 64 k-cols)
        f32x4 s[4];
#pragma unroll
        for (int f = 0; f < 4; ++f) {
            f32x4 z = {};
            const bf16x8 kb0 = *reinterpret_cast<const bf16x8*>(Kt + (f * 16 + lr) * 72 + lg * 8);
            const bf16x8 kb1 = *reinterpret_cast<const bf16x8*>(Kt + (f * 16 + lr) * 72 + 32 + lg * 8);
            z = __builtin_amdgcn_mfma_f32_16x16x32_bf16(qa0, kb0, z, 0, 0, 0);
            z = __builtin_amdgcn_mfma_f32_16x16x32_bf16(qa1, kb1, z, 0, 0, 0);
            s[f] = z;
        }

        const int qrow_b = qt * 64 + w * 16 + lg * 4;  // + j
        const bool diag = (kt == qt);
#pragma unroll
        for (int f = 0; f < 4; ++f) {
            const int colg = kt * 64 + f * 16 + lr;
#pragma unroll
            for (int j = 0; j < 4; ++j) {
                float v = s[f][j] * 0.125f;           // scaling = D^-0.5
                if (diag && colg > qrow_b + j) v = -3.0e38f;
                s[f][j] = v;
            }
        }

        // online softmax (rows live in 16-lane groups; reduce via shfl_xor)
        float mnew[4], rsc[4];
#pragma unroll
        for (int j = 0; j < 4; ++j) {
            float t = fmaxf(fmaxf(s[0][j], s[1][j]), fmaxf(s[2][j], s[3][j]));
            t = fmaxf(t, __shfl_xor(t, 1));
            t = fmaxf(t, __shfl_xor(t, 2));
            t = fmaxf(t, __shfl_xor(t, 4));
            t = fmaxf(t, __shfl_xor(t, 8));
            mnew[j] = fmaxf(mr[j], t);
            rsc[j] = __expf(mr[j] - mnew[j]);
            mr[j] = mnew[j];
        }
#pragma unroll
        for (int f = 0; f < 4; ++f)
#pragma unroll
            for (int j = 0; j < 4; ++j)
                s[f][j] = __expf(s[f][j] - mnew[j]);
#pragma unroll
        for (int j = 0; j < 4; ++j) {
            float t = s[0][j] + s[1][j] + s[2][j] + s[3][j];
            t += __shfl_xor(t, 1);
            t += __shfl_xor(t, 2);
            t += __shfl_xor(t, 4);
            t += __shfl_xor(t, 8);
            ls[j] = ls[j] * rsc[j] + t;
#pragma unroll
            for (int f2 = 0; f2 < 4; ++f2) o[f2][j] *= rsc[j];
        }

        // P -> LDS (bf16) in row-major, then read back as MFMA A-fragments
        bf16_t* pw = &Pl[w][0];
#pragma unroll
        for (int f = 0; f < 4; ++f)
#pragma unroll
            for (int j = 0; j < 4; ++j)
                pw[(lg * 4 + j) * 72 + f * 16 + lr] = (bf16_t)s[f][j];

        const bf16x8 pa0 = *reinterpret_cast<const bf16x8*>(pw + lr * 72 + lg * 8);
        const bf16x8 pa1 = *reinterpret_cast<const bf16x8*>(pw + lr * 72 + 32 + lg * 8);
#pragma unroll
        for (int f2 = 0; f2 < 4; ++f2) {
            const bf16x8 vb0 = *reinterpret_cast<const bf16x8*>(Vt + (f2 * 16 + lr) * 72 + lg * 8);
            const bf16x8 vb1 = *reinterpret_cast<const bf16x8*>(Vt + (f2 * 16 + lr) * 72 + 32 + lg * 8);
            o[f2] = __builtin_amdgcn_mfma_f32_16x16x32_bf16(pa0, vb0, o[f2], 0, 0, 0);
            o[f2] = __builtin_amdgcn_mfma_f32_16x16x32_bf16(pa1, vb1, o[f2], 0, 0, 0);
        }
    }

    // epilogue: normalize and store
    const size_t obase = (size_t)(sq * SEQLEN + qt * 64 + w * 16 + lg * 4) * E_DIM + h * 64 + lr;
#pragma unroll
    for (int j = 0; j < 4; ++j) {
        const float inv = 1.0f / ls[j];
#pragma unroll
        for (int f2 = 0; f2 < 4; ++f2)
            Og[obase + (size_t)j * E_DIM + f2 * 16] = (bf16_t)(o[f2][j] * inv);
    }
}

// ---------------------------------------------------------------------------
extern "C" void kernel_launch(void* const* d_in, const int* in_sizes, int n_in,
                              void* d_out, int out_size, void* d_ws, size_t ws_size,
                              hipStream_t stream) {
    const float* hid = (const float*)d_in[0];
    const float* Wq  = (const float*)d_in[1];
    const float* bq  = (const float*)d_in[2];
    const float* Wk  = (const float*)d_in[3];
    const float* bk  = (const float*)d_in[4];
    const float* Wv  = (const float*)d_in[5];
    const float* bv  = (const float*)d_in[6];
    const float* Wo  = (const float*)d_in[7];
    const float* bo  = (const float*)d_in[8];
    float* out = (float*)d_out;

    const size_t TE = (size_t)T_TOK * E_DIM;   // 16,777,216
    const size_t EE = (size_t)E_DIM * E_DIM;   //  4,194,304

    bf16_t* ws   = (bf16_t*)d_ws;
    bf16_t* hidB = ws;            // reused as attention output later
    bf16_t* WqB  = ws + TE;
    bf16_t* WkB  = WqB + EE;
    bf16_t* WvB  = WkB + EE;
    bf16_t* WoB  = WvB + EE;
    bf16_t* qB   = WoB + EE;
    bf16_t* kB   = qB + TE;
    bf16_t* vB   = kB + TE;

    cvt_f32_bf16<<<2048, 256, 0, stream>>>(hid, hidB, (int)(TE / 4));
    cvt_f32_bf16<<<1024, 256, 0, stream>>>(Wq, WqB, (int)(EE / 4));
    cvt_f32_bf16<<<1024, 256, 0, stream>>>(Wk, WkB, (int)(EE / 4));
    cvt_f32_bf16<<<1024, 256, 0, stream>>>(Wv, WvB, (int)(EE / 4));
    cvt_f32_bf16<<<1024, 256, 0, stream>>>(Wo, WoB, (int)(EE / 4));

    dim3 gg(T_TOK / 128, E_DIM / 128), bb(256);
    gemm_bt<true><<<gg, bb, 0, stream>>>(hidB, WqB, bq, qB, T_TOK, E_DIM, E_DIM);
    gemm_bt<true><<<gg, bb, 0, stream>>>(hidB, WkB, bk, kB, T_TOK, E_DIM, E_DIM);
    gemm_bt<true><<<gg, bb, 0, stream>>>(hidB, WvB, bv, vB, T_TOK, E_DIM, E_DIM);

    attn_fwd<<<dim3(16, NHEAD, NSEQ), 256, 0, stream>>>(qB, kB, vB, hidB);

    gemm_bt<false><<<gg, bb, 0, stream>>>(hidB, WoB, bo, out, T_TOK, E_DIM, E_DIM);
}

// Round 2
// 461.130 us; speedup vs baseline: 1.3004x; 1.3004x over previous
//
#include <hip/hip_runtime.h>
#include <hip/hip_bf16.h>

typedef __bf16 bf16_t;
typedef __bf16 bf16x8 __attribute__((ext_vector_type(8)));
typedef __bf16 bf16x4 __attribute__((ext_vector_type(4)));
typedef float f32x4 __attribute__((ext_vector_type(4)));
typedef float f32x16 __attribute__((ext_vector_type(16)));
typedef unsigned short u16x8 __attribute__((ext_vector_type(8)));
typedef unsigned int u32x4 __attribute__((ext_vector_type(4)));

#define T_TOK 8192
#define E_DIM 2048
#define NHEAD 32
#define SEQLEN 1024
#define NSEQ 8

#if __has_builtin(__builtin_amdgcn_exp2f)
#define EXP2F(x) __builtin_amdgcn_exp2f(x)
#else
#define EXP2F(x) exp2f(x)
#endif

static __device__ inline unsigned cvtpk_bf16(float lo, float hi) {
    unsigned r;
    asm("v_cvt_pk_bf16_f32 %0, %1, %2" : "=v"(r) : "v"(lo), "v"(hi));
    return r;
}

// exchange: x' = [x_low | y_low-from-partner], y' = [x_high-from-partner | y_high]
static __device__ inline void plswap(unsigned &x, unsigned &y, bool lo_half) {
#if __has_builtin(__builtin_amdgcn_permlane32_swap)
    auto r = __builtin_amdgcn_permlane32_swap(x, y, false, false);
    x = r[0]; y = r[1];
#else
    unsigned xs = __shfl_xor(x, 32), ys = __shfl_xor(y, 32);
    unsigned nx = lo_half ? x : ys;
    unsigned ny = lo_half ? xs : y;
    x = nx; y = ny;
#endif
}

// ---------------- fp32 -> bf16 conversion (vectorized, grid-stride) --------
__global__ void cvt_f32_bf16(const float* __restrict__ in, bf16_t* __restrict__ out, int n4) {
    int idx = blockIdx.x * blockDim.x + threadIdx.x;
    int stride = gridDim.x * blockDim.x;
    for (int i = idx; i < n4; i += stride) {
        const float4 v = reinterpret_cast<const float4*>(in)[i];
        bf16x4 o;
        o[0] = (bf16_t)v.x; o[1] = (bf16_t)v.y; o[2] = (bf16_t)v.z; o[3] = (bf16_t)v.w;
        reinterpret_cast<bf16x4*>(out)[i] = o;
    }
}

// ---------------- GEMM: C[M,N] = (A[M,K] * B[N,K]^T + bias) * outScale -----
template<bool OUT_BF16>
__global__ __launch_bounds__(256, 2)
void gemm_bt(const bf16_t* __restrict__ A, const bf16_t* __restrict__ B,
             const float* __restrict__ bias, void* __restrict__ Cout,
             int M, int N, int K, float outScale) {
    __shared__ alignas(16) bf16_t aT[128 * 32];
    __shared__ alignas(16) bf16_t bT[128 * 32];
    const int tid = threadIdx.x;
    const int w = tid >> 6, l = tid & 63;
    const int bm = blockIdx.x, bn = blockIdx.y;
    const int wr = (w >> 1) * 64, wc = (w & 1) * 64;
    const int rowf = l & 15, kg = (l >> 4) * 8;

    f32x4 acc[4][4] = {};

    const int srow = l >> 2;
    const int scol = (l & 3) * 8;
    const bf16_t* aBase = A + (size_t)(bm * 128) * K;
    const bf16_t* bBase = B + (size_t)(bn * 128) * K;

    for (int k0 = 0; k0 < K; k0 += 32) {
        __syncthreads();
#pragma unroll
        for (int c = 0; c < 2; ++c) {
            const int row = (w * 2 + c) * 16 + srow;
            __builtin_amdgcn_global_load_lds(
                (const __attribute__((address_space(1))) void*)(aBase + (size_t)row * K + k0 + scol),
                (__attribute__((address_space(3))) void*)(aT + (w * 2 + c) * 512), 16, 0, 0);
            __builtin_amdgcn_global_load_lds(
                (const __attribute__((address_space(1))) void*)(bBase + (size_t)row * K + k0 + scol),
                (__attribute__((address_space(3))) void*)(bT + (w * 2 + c) * 512), 16, 0, 0);
        }
        __syncthreads();

        bf16x8 af[4], bfr[4];
#pragma unroll
        for (int i = 0; i < 4; ++i)
            af[i] = *reinterpret_cast<const bf16x8*>(aT + (wr + i * 16 + rowf) * 32 + kg);
#pragma unroll
        for (int j = 0; j < 4; ++j)
            bfr[j] = *reinterpret_cast<const bf16x8*>(bT + (wc + j * 16 + rowf) * 32 + kg);
#pragma unroll
        for (int i = 0; i < 4; ++i)
#pragma unroll
            for (int j = 0; j < 4; ++j)
                acc[i][j] = __builtin_amdgcn_mfma_f32_16x16x32_bf16(af[i], bfr[j], acc[i][j], 0, 0, 0);
    }

    const int r0 = bm * 128 + wr + (l >> 4) * 4;
    const int c0 = bn * 128 + wc + (l & 15);
#pragma unroll
    for (int jf = 0; jf < 4; ++jf) {
        const int col = c0 + jf * 16;
        const float bb = bias[col];
#pragma unroll
        for (int i = 0; i < 4; ++i) {
#pragma unroll
            for (int j = 0; j < 4; ++j) {
                const int row = r0 + i * 16 + j;
                const float v = (acc[i][jf][j] + bb) * outScale;
                if (OUT_BF16)
                    ((bf16_t*)Cout)[(size_t)row * N + col] = (bf16_t)v;
                else
                    ((float*)Cout)[(size_t)row * N + col] = v;
            }
        }
    }
}

// ---------------- Flash attention, 8-wave 32x32 swapped-QK^T ---------------
// Q-tile 256 rows (32/wave), KVBLK=128, D=64. Q is PRE-SCALED by 0.125*log2e
// (folded into the Q GEMM), so softmax runs in exp2 domain.
// S^T = mfma(K,Q): lane owns q-column (l&31); O^T = mfma(V^T,P): lane-local 1/l.
__global__ __launch_bounds__(512, 2)
void attn_fwd2(const bf16_t* __restrict__ Qg, const bf16_t* __restrict__ Kg,
               const bf16_t* __restrict__ Vg, bf16_t* __restrict__ Og) {
    // XCD-aware decode: the 4 q-blocks of one (h,seq) land on one XCD.
    const int n = blockIdx.x;            // 0..1023
    const int i = n >> 3;
    const int grp = (n & 7) * 32 + (i >> 2);  // 0..255 -> (h, sq)
    const int qt = i & 3;
    const int h = grp & 31;
    const int sq = grp >> 5;

    const int tid = threadIdx.x;
    const int w = tid >> 6;
    const int l = tid & 63;
    const int ll = l & 31;
    const int hi = l >> 5;
    const bool lo_half = (hi == 0);

    __shared__ alignas(16) unsigned char lds[65536];  // K[2][16KB] + V[2][16KB]

    const size_t kvbase = (size_t)(sq * SEQLEN) * E_DIM + h * 64;

    // Q fragments (B-operand): row q = l&31, d = dc*16 + hi*8 + 0..7
    const int q_glob = qt * 256 + w * 32 + ll;
    const bf16_t* qp = Qg + (size_t)(sq * SEQLEN + q_glob) * E_DIM + h * 64 + hi * 8;
    bf16x8 qf[4];
#pragma unroll
    for (int dc = 0; dc < 4; ++dc)
        qf[dc] = *reinterpret_cast<const bf16x8*>(qp + dc * 16);

    const int nkt = 2 * qt + 2;
    const int q_wave_max = qt * 256 + w * 32 + 31;

    f32x16 oac[2] = {};
    float mrun = -3.0e38f, lsum = 0.f;

    // staging state
    bf16x8 vr0, vr1;
    const int vk0 = l * 2;    // k pair within tile
    const int vd0 = w * 8;    // d range

    auto stageK = [&](int kt, int buf) {   // K[128][64] linear+swz via pre-swizzled src
#pragma unroll
        for (int c = 0; c < 2; ++c) {
            const int o = (w * 2 + c) * 1024 + l * 16;
            const int r = o >> 7;
            const int swb = (o & 127) ^ ((r & 7) << 4);
            const bf16_t* src = Kg + kvbase + (size_t)(kt * 128 + r) * E_DIM + (swb >> 1);
            __builtin_amdgcn_global_load_lds(
                (const __attribute__((address_space(1))) void*)src,
                (__attribute__((address_space(3))) void*)(lds + buf * 16384 + (w * 2 + c) * 1024),
                16, 0, 0);
        }
    };
    auto loadV = [&](int kt) {
        const bf16_t* vp = Vg + kvbase + (size_t)(kt * 128 + vk0) * E_DIM + vd0;
        vr0 = *reinterpret_cast<const bf16x8*>(vp);
        vr1 = *reinterpret_cast<const bf16x8*>(vp + E_DIM);
    };
    auto writeV = [&](int buf) {           // V^T[64][128] with XOR swizzle
        u16x8 s0 = __builtin_bit_cast(u16x8, vr0);
        u16x8 s1 = __builtin_bit_cast(u16x8, vr1);
        unsigned char* vb = lds + 32768 + buf * 16384;
#pragma unroll
        for (int e = 0; e < 8; ++e) {
            const int d = vd0 + e;
            unsigned off = (unsigned)(d * 256 + vk0 * 2);
            off ^= ((unsigned)((d ^ (d >> 4)) & 15)) << 4;
            *reinterpret_cast<unsigned*>(vb + off) = (unsigned)s0[e] | ((unsigned)s1[e] << 16);
        }
    };

    stageK(0, 0);
    loadV(0);
    writeV(0);
    __syncthreads();

    const unsigned ksw = (unsigned)((l & 7) << 4);
    const unsigned kbase = (unsigned)(ll * 128 + hi * 16);

    int cur = 0;
    for (int kt = 0; kt < nkt; ++kt) {
        const bool notlast = (kt + 1 < nkt);
        if (notlast) { stageK(kt + 1, cur ^ 1); loadV(kt + 1); }

        if (kt * 128 <= q_wave_max) {   // wave-uniform: skip fully-masked tiles
            const unsigned char* Kcur = lds + cur * 16384;
            const unsigned char* Vcur = lds + 32768 + cur * 16384;

            // S^T[k=128][q=32] = mfma(K, Q), 4 kh tiles
            f32x16 st[4];
#pragma unroll
            for (int kh = 0; kh < 4; ++kh) {
                f32x16 acc = {};
#pragma unroll
                for (int dc = 0; dc < 4; ++dc) {
                    const unsigned off = (kbase + (unsigned)(kh * 4096 + dc * 32)) ^ ksw;
                    const bf16x8 ka = *reinterpret_cast<const bf16x8*>(Kcur + off);
                    acc = __builtin_amdgcn_mfma_f32_32x32x16_bf16(ka, qf[dc], acc, 0, 0, 0);
                }
                st[kh] = acc;
            }

            // causal mask (diagonal-region tiles only)
            if (kt >= 2 * qt) {
#pragma unroll
                for (int kh = 0; kh < 4; ++kh)
#pragma unroll
                    for (int r = 0; r < 16; ++r) {
                        const int kg = kt * 128 + kh * 32 + (r & 3) + 8 * (r >> 2) + 4 * hi;
                        if (kg > q_glob) st[kh][r] = -3.0e38f;
                    }
            }

            // online softmax (exp2 domain), lane pair (l, l^32) holds one q-row
            float tm = -3.0e38f;
#pragma unroll
            for (int kh = 0; kh < 4; ++kh)
#pragma unroll
                for (int r = 0; r < 16; ++r) tm = fmaxf(tm, st[kh][r]);
            tm = fmaxf(tm, __shfl_xor(tm, 32));

            if (!__all(tm <= mrun + 8.0f)) {   // defer-max (THR=8 in log2 units)
                const float mnew = fmaxf(mrun, tm);
                const float rsc = EXP2F(mrun - mnew);
                mrun = mnew;
                lsum *= rsc;
#pragma unroll
                for (int dh = 0; dh < 2; ++dh)
#pragma unroll
                    for (int r = 0; r < 16; ++r) oac[dh][r] *= rsc;
            }

            float ps = 0.f;
#pragma unroll
            for (int kh = 0; kh < 4; ++kh)
#pragma unroll
                for (int r = 0; r < 16; ++r) {
                    const float p = EXP2F(st[kh][r] - mrun);
                    st[kh][r] = p;
                    ps += p;
                }
            ps += __shfl_xor(ps, 32);
            lsum += ps;

            // P -> bf16 A-operand frags via cvt_pk + permlane32_swap
            bf16x8 pf[8];
#pragma unroll
            for (int kh = 0; kh < 4; ++kh)
#pragma unroll
                for (int hc = 0; hc < 2; ++hc) {
                    const int b0 = hc * 8;
                    unsigned a  = cvtpk_bf16(st[kh][b0 + 0], st[kh][b0 + 1]);
                    unsigned b  = cvtpk_bf16(st[kh][b0 + 4], st[kh][b0 + 5]);
                    unsigned a2 = cvtpk_bf16(st[kh][b0 + 2], st[kh][b0 + 3]);
                    unsigned b2 = cvtpk_bf16(st[kh][b0 + 6], st[kh][b0 + 7]);
                    plswap(a, b, lo_half);
                    plswap(a2, b2, lo_half);
                    u32x4 words = { a, a2, b, b2 };
                    pf[kh * 2 + hc] = __builtin_bit_cast(bf16x8, words);
                }

            // O^T[d=64][q=32] += mfma(V^T, P)
#pragma unroll
            for (int dh = 0; dh < 2; ++dh) {
                const int d = dh * 32 + ll;
                const unsigned vsw = ((unsigned)((d ^ (d >> 4)) & 15)) << 4;
                const unsigned vbb = (unsigned)(d * 256 + hi * 16);
#pragma unroll
                for (int kc = 0; kc < 8; ++kc) {
                    const unsigned off = (vbb + (unsigned)(kc * 32)) ^ vsw;
                    const bf16x8 vfr = *reinterpret_cast<const bf16x8*>(Vcur + off);
                    oac[dh] = __builtin_amdgcn_mfma_f32_32x32x16_bf16(vfr, pf[kc], oac[dh], 0, 0, 0);
                }
            }
        }

        if (notlast) writeV(cur ^ 1);
        __syncthreads();
        cur ^= 1;
    }

    // epilogue: lane-local normalize, 8B stores (reg quads are d-consecutive)
    const float inv = 1.0f / lsum;
    bf16_t* op = Og + (size_t)(sq * SEQLEN + q_glob) * E_DIM + h * 64;
#pragma unroll
    for (int dh = 0; dh < 2; ++dh)
#pragma unroll
        for (int rq = 0; rq < 4; ++rq) {
            const int d0 = dh * 32 + 8 * rq + 4 * hi;
            bf16x4 ov;
#pragma unroll
            for (int j = 0; j < 4; ++j)
                ov[j] = (bf16_t)(oac[dh][rq * 4 + j] * inv);
            *reinterpret_cast<bf16x4*>(op + d0) = ov;
        }
}

// ---------------------------------------------------------------------------
extern "C" void kernel_launch(void* const* d_in, const int* in_sizes, int n_in,
                              void* d_out, int out_size, void* d_ws, size_t ws_size,
                              hipStream_t stream) {
    const float* hid = (const float*)d_in[0];
    const float* Wq  = (const float*)d_in[1];
    const float* bq  = (const float*)d_in[2];
    const float* Wk  = (const float*)d_in[3];
    const float* bk  = (const float*)d_in[4];
    const float* Wv  = (const float*)d_in[5];
    const float* bv  = (const float*)d_in[6];
    const float* Wo  = (const float*)d_in[7];
    const float* bo  = (const float*)d_in[8];
    float* out = (float*)d_out;

    const size_t TE = (size_t)T_TOK * E_DIM;
    const size_t EE = (size_t)E_DIM * E_DIM;

    bf16_t* ws   = (bf16_t*)d_ws;
    bf16_t* hidB = ws;            // reused as attention output later
    bf16_t* WqB  = ws + TE;
    bf16_t* WkB  = WqB + EE;
    bf16_t* WvB  = WkB + EE;
    bf16_t* WoB  = WvB + EE;
    bf16_t* qB   = WoB + EE;
    bf16_t* kB   = qB + TE;
    bf16_t* vB   = kB + TE;

    cvt_f32_bf16<<<2048, 256, 0, stream>>>(hid, hidB, (int)(TE / 4));
    cvt_f32_bf16<<<1024, 256, 0, stream>>>(Wq, WqB, (int)(EE / 4));
    cvt_f32_bf16<<<1024, 256, 0, stream>>>(Wk, WkB, (int)(EE / 4));
    cvt_f32_bf16<<<1024, 256, 0, stream>>>(Wv, WvB, (int)(EE / 4));
    cvt_f32_bf16<<<1024, 256, 0, stream>>>(Wo, WoB, (int)(EE / 4));

    // Q is pre-scaled by D^-0.5 * log2(e) so attention works in exp2 domain.
    const float QSCALE = 0.125f * 1.4426950408889634f;
    dim3 gg(T_TOK / 128, E_DIM / 128), bb(256);
    gemm_bt<true><<<gg, bb, 0, stream>>>(hidB, WqB, bq, qB, T_TOK, E_DIM, E_DIM, QSCALE);
    gemm_bt<true><<<gg, bb, 0, stream>>>(hidB, WkB, bk, kB, T_TOK, E_DIM, E_DIM, 1.0f);
    gemm_bt<true><<<gg, bb, 0, stream>>>(hidB, WvB, bv, vB, T_TOK, E_DIM, E_DIM, 1.0f);

    attn_fwd2<<<dim3(1024), 512, 0, stream>>>(qB, kB, vB, hidB);

    gemm_bt<false><<<gg, bb, 0, stream>>>(hidB, WoB, bo, out, T_TOK, E_DIM, E_DIM, 1.0f);
}

// Round 3
// 413.566 us; speedup vs baseline: 1.4500x; 1.1150x over previous
//
#include <hip/hip_runtime.h>
#include <hip/hip_bf16.h>

typedef __bf16 bf16_t;
typedef __bf16 bf16x8 __attribute__((ext_vector_type(8)));
typedef __bf16 bf16x4 __attribute__((ext_vector_type(4)));
typedef float f32x4 __attribute__((ext_vector_type(4)));
typedef float f32x16 __attribute__((ext_vector_type(16)));
typedef unsigned short u16x8 __attribute__((ext_vector_type(8)));
typedef unsigned int u32x4 __attribute__((ext_vector_type(4)));

#define T_TOK 8192
#define E_DIM 2048
#define NHEAD 32
#define SEQLEN 1024
#define NSEQ 8
#define LDQ 6144

#if __has_builtin(__builtin_amdgcn_exp2f)
#define EXP2F(x) __builtin_amdgcn_exp2f(x)
#else
#define EXP2F(x) exp2f(x)
#endif

static __device__ inline unsigned cvtpk_bf16(float lo, float hi) {
    unsigned r;
    asm("v_cvt_pk_bf16_f32 %0, %1, %2" : "=v"(r) : "v"(lo), "v"(hi));
    return r;
}

static __device__ inline void plswap(unsigned &x, unsigned &y, bool lo_half) {
#if __has_builtin(__builtin_amdgcn_permlane32_swap)
    auto r = __builtin_amdgcn_permlane32_swap(x, y, false, false);
    x = r[0]; y = r[1];
#else
    unsigned xs = __shfl_xor(x, 32), ys = __shfl_xor(y, 32);
    unsigned nx = lo_half ? x : ys;
    unsigned ny = lo_half ? xs : y;
    x = nx; y = ny;
#endif
}

// ---------------- fp32 -> bf16 conversion (vectorized, grid-stride) --------
__global__ void cvt_f32_bf16(const float* __restrict__ in, bf16_t* __restrict__ out, int n4) {
    int idx = blockIdx.x * blockDim.x + threadIdx.x;
    int stride = gridDim.x * blockDim.x;
    for (int i = idx; i < n4; i += stride) {
        const float4 v = reinterpret_cast<const float4*>(in)[i];
        bf16x4 o;
        o[0] = (bf16_t)v.x; o[1] = (bf16_t)v.y; o[2] = (bf16_t)v.z; o[3] = (bf16_t)v.w;
        reinterpret_cast<bf16x4*>(out)[i] = o;
    }
}

// ---------------- GEMM 256x256, BK=32, depth-2 counted-vmcnt pipeline ------
// C[M,N] = (A[M,K] * B[N,K]^T + bias) * (col<qlim ? qs : 1)
// 8 waves (2M x 4N), per-wave 128x64. LDS 64KB (2 buf x (A 16K + B 16K)).
// Swizzle: byte col ^= ((row>>1)&3)<<4 (both on pre-swizzled global src and read).
template<bool OUT_BF16>
__global__ __launch_bounds__(512, 2)
void gemm256(const bf16_t* __restrict__ A, const bf16_t* __restrict__ B,
             const float* __restrict__ b0, const float* __restrict__ b1,
             const float* __restrict__ b2, void* __restrict__ Cout,
             int M, int N, int K, float qs, int qlim) {
    __shared__ alignas(16) unsigned char lds[65536];
    const int tid = threadIdx.x;
    const int wid = tid >> 6, l = tid & 63;
    // XCD bijective swizzle (nwg divisible by 8)
    const int cpx = gridDim.x >> 3;
    const int wg = (blockIdx.x & 7) * cpx + (blockIdx.x >> 3);
    const int nbm = M >> 8;
    const int bm = wg % nbm, bn = wg / nbm;
    const int wrow = (wid >> 2) * 128, wcol = (wid & 3) * 64;
    const int lr = l & 15, lg = l >> 4;

    f32x4 acc[8][4] = {};

    const int sr = l >> 2;           // row within 16-row stage chunk
    const int scb = (l & 3) * 16;    // chunk byte within 64B row
    const bf16_t* aBase = A + (size_t)(bm * 256) * K;
    const bf16_t* bBase = B + (size_t)(bn * 256) * K;

    auto stage = [&](int kt, int b) {
        unsigned char* base = lds + b * 32768;
#pragma unroll
        for (int c = 0; c < 2; ++c) {
            const int r = (wid * 2 + c) * 16 + sr;
            const int cbs = scb ^ (((r >> 1) & 3) << 4);
            __builtin_amdgcn_global_load_lds(
                (const __attribute__((address_space(1))) void*)(aBase + (size_t)r * K + kt * 32 + (cbs >> 1)),
                (__attribute__((address_space(3))) void*)(base + (wid * 2 + c) * 1024), 16, 0, 0);
            __builtin_amdgcn_global_load_lds(
                (const __attribute__((address_space(1))) void*)(bBase + (size_t)r * K + kt * 32 + (cbs >> 1)),
                (__attribute__((address_space(3))) void*)(base + 16384 + (wid * 2 + c) * 1024), 16, 0, 0);
        }
    };

    const int nk = K >> 5;
    stage(0, 0);
    stage(1, 1);
    asm volatile("s_waitcnt vmcnt(4)" ::: "memory");
    __builtin_amdgcn_s_barrier();

    int b = 0;
    for (int kt = 0; kt < nk; ++kt) {
        const unsigned char* Ab = lds + b * 32768;
        bf16x8 af[8], bfv[4];
#pragma unroll
        for (int m = 0; m < 8; ++m) {
            const int r = wrow + m * 16 + lr;
            const int cb = (lg * 16) ^ (((r >> 1) & 3) << 4);
            af[m] = *reinterpret_cast<const bf16x8*>(Ab + r * 64 + cb);
        }
#pragma unroll
        for (int n = 0; n < 4; ++n) {
            const int r = wcol + n * 16 + lr;
            const int cb = (lg * 16) ^ (((r >> 1) & 3) << 4);
            bfv[n] = *reinterpret_cast<const bf16x8*>(Ab + 16384 + r * 64 + cb);
        }
        __builtin_amdgcn_s_setprio(1);
#pragma unroll
        for (int m = 0; m < 8; ++m)
#pragma unroll
            for (int n = 0; n < 4; ++n)
                acc[m][n] = __builtin_amdgcn_mfma_f32_16x16x32_bf16(af[m], bfv[n], acc[m][n], 0, 0, 0);
        __builtin_amdgcn_s_setprio(0);
        if (kt == nk - 1) break;
        asm volatile("s_waitcnt lgkmcnt(0)" ::: "memory");   // all ds_reads of buf b returned
        __builtin_amdgcn_sched_barrier(0);
        __builtin_amdgcn_s_barrier();                         // buf b now dead everywhere
        if (kt + 2 < nk) {
            stage(kt + 2, b);                                 // overwrite buf b for t+2
            asm volatile("s_waitcnt vmcnt(4)" ::: "memory");  // tile t+1 fully landed
        } else {
            asm volatile("s_waitcnt vmcnt(0)" ::: "memory");
        }
        __builtin_amdgcn_s_barrier();                         // publish t+1
        b ^= 1;
    }

    // epilogue: C[row=(l>>4)*4+j][col=l&15] per fragment
    const int r0 = bm * 256 + wrow + lg * 4;
    const int c0 = bn * 256 + wcol + lr;
#pragma unroll
    for (int n = 0; n < 4; ++n) {
        const int cc = c0 + n * 16;
        const float bias = (cc < 2048) ? b0[cc] : (cc < 4096 ? b1[cc - 2048] : b2[cc - 4096]);
        const float sc = (cc < qlim) ? qs : 1.0f;
#pragma unroll
        for (int m = 0; m < 8; ++m)
#pragma unroll
            for (int j = 0; j < 4; ++j) {
                const int rr = r0 + m * 16 + j;
                const float v = (acc[m][n][j] + bias) * sc;
                if (OUT_BF16) ((bf16_t*)Cout)[(size_t)rr * N + cc] = (bf16_t)v;
                else          ((float*)Cout)[(size_t)rr * N + cc] = v;
            }
    }
}

// ---------------- Flash attention, 8-wave 32x32 swapped-QK^T, paired qt ----
// Block handles two q-tiles {0,3} or {1,2} of one (h,seq): uniform 10 k-stages.
// QKV fused layout, row stride LDQ=6144 (q +0, k +2048, v +4096).
__global__ __launch_bounds__(512, 2)
void attn_fwd3(const bf16_t* __restrict__ QKV, bf16_t* __restrict__ Og) {
    const int orig = blockIdx.x;               // 0..511
    const int id = (orig & 7) * 64 + (orig >> 3);
    const int grp = id >> 1;                   // (h, sq)
    const int pairIdx = id & 1;
    const int h = grp & 31;
    const int sq = grp >> 5;

    const int tid = threadIdx.x;
    const int w = tid >> 6;
    const int l = tid & 63;
    const int ll = l & 31;
    const int hi = l >> 5;
    const bool lo_half = (hi == 0);

    __shared__ alignas(16) unsigned char lds[65536];  // K[2][16KB] + V[2][16KB]

    const bf16_t* Qg = QKV;
    const bf16_t* Kg = QKV + 2048;
    const bf16_t* Vg = QKV + 4096;
    const size_t kvbase = (size_t)(sq * SEQLEN) * LDQ + h * 64;

    bf16x8 vr0, vr1;
    const int vk0 = l * 2;
    const int vd0 = w * 8;

    auto stageK = [&](int kt, int buf) {
#pragma unroll
        for (int c = 0; c < 2; ++c) {
            const int o = (w * 2 + c) * 1024 + l * 16;
            const int r = o >> 7;
            const int swb = (o & 127) ^ ((r & 7) << 4);
            const bf16_t* src = Kg + kvbase + (size_t)(kt * 128 + r) * LDQ + (swb >> 1);
            __builtin_amdgcn_global_load_lds(
                (const __attribute__((address_space(1))) void*)src,
                (__attribute__((address_space(3))) void*)(lds + buf * 16384 + (w * 2 + c) * 1024),
                16, 0, 0);
        }
    };
    auto loadV = [&](int kt) {
        const bf16_t* vp = Vg + kvbase + (size_t)(kt * 128 + vk0) * LDQ + vd0;
        vr0 = *reinterpret_cast<const bf16x8*>(vp);
        vr1 = *reinterpret_cast<const bf16x8*>(vp + LDQ);
    };
    auto writeV = [&](int buf) {
        u16x8 s0 = __builtin_bit_cast(u16x8, vr0);
        u16x8 s1 = __builtin_bit_cast(u16x8, vr1);
        unsigned char* vb = lds + 32768 + buf * 16384;
#pragma unroll
        for (int e = 0; e < 8; ++e) {
            const int d = vd0 + e;
            unsigned off = (unsigned)(d * 256 + vk0 * 2);
            off ^= ((unsigned)((d ^ (d >> 4)) & 15)) << 4;
            *reinterpret_cast<unsigned*>(vb + off) = (unsigned)s0[e] | ((unsigned)s1[e] << 16);
        }
    };

    const unsigned ksw = (unsigned)((l & 7) << 4);
    const unsigned kbase = (unsigned)(ll * 128 + hi * 16);

#pragma unroll 1
    for (int seg = 0; seg < 2; ++seg) {
        const int qt = pairIdx ? (seg ? 2 : 1) : (seg ? 3 : 0);

        const int q_glob = qt * 256 + w * 32 + ll;
        const bf16_t* qp = Qg + (size_t)(sq * SEQLEN + q_glob) * LDQ + h * 64 + hi * 8;
        bf16x8 qf[4];
#pragma unroll
        for (int dc = 0; dc < 4; ++dc)
            qf[dc] = *reinterpret_cast<const bf16x8*>(qp + dc * 16);

        const int nkt = 2 * qt + 2;
        const int q_wave_max = qt * 256 + w * 32 + 31;

        f32x16 oac[2] = {};
        float mrun = -3.0e38f, lsum = 0.f;

        stageK(0, 0);
        loadV(0);
        writeV(0);
        __syncthreads();

        int cur = 0;
        for (int kt = 0; kt < nkt; ++kt) {
            const bool notlast = (kt + 1 < nkt);
            if (notlast) { stageK(kt + 1, cur ^ 1); loadV(kt + 1); }

            if (kt * 128 <= q_wave_max) {
                const unsigned char* Kcur = lds + cur * 16384;
                const unsigned char* Vcur = lds + 32768 + cur * 16384;

                f32x16 st[4];
#pragma unroll
                for (int kh = 0; kh < 4; ++kh) {
                    f32x16 acc = {};
#pragma unroll
                    for (int dc = 0; dc < 4; ++dc) {
                        const unsigned off = (kbase + (unsigned)(kh * 4096 + dc * 32)) ^ ksw;
                        const bf16x8 ka = *reinterpret_cast<const bf16x8*>(Kcur + off);
                        acc = __builtin_amdgcn_mfma_f32_32x32x16_bf16(ka, qf[dc], acc, 0, 0, 0);
                    }
                    st[kh] = acc;
                }

                if (kt >= 2 * qt) {
#pragma unroll
                    for (int kh = 0; kh < 4; ++kh)
#pragma unroll
                        for (int r = 0; r < 16; ++r) {
                            const int kg = kt * 128 + kh * 32 + (r & 3) + 8 * (r >> 2) + 4 * hi;
                            if (kg > q_glob) st[kh][r] = -3.0e38f;
                        }
                }

                float tm = -3.0e38f;
#pragma unroll
                for (int kh = 0; kh < 4; ++kh)
#pragma unroll
                    for (int r = 0; r < 16; ++r) tm = fmaxf(tm, st[kh][r]);
                tm = fmaxf(tm, __shfl_xor(tm, 32));

                if (!__all(tm <= mrun + 8.0f)) {
                    const float mnew = fmaxf(mrun, tm);
                    const float rsc = EXP2F(mrun - mnew);
                    mrun = mnew;
                    lsum *= rsc;
#pragma unroll
                    for (int dh = 0; dh < 2; ++dh)
#pragma unroll
                        for (int r = 0; r < 16; ++r) oac[dh][r] *= rsc;
                }

                float ps = 0.f;
#pragma unroll
                for (int kh = 0; kh < 4; ++kh)
#pragma unroll
                    for (int r = 0; r < 16; ++r) {
                        const float p = EXP2F(st[kh][r] - mrun);
                        st[kh][r] = p;
                        ps += p;
                    }
                ps += __shfl_xor(ps, 32);
                lsum += ps;

                bf16x8 pf[8];
#pragma unroll
                for (int kh = 0; kh < 4; ++kh)
#pragma unroll
                    for (int hc = 0; hc < 2; ++hc) {
                        const int b0i = hc * 8;
                        unsigned a  = cvtpk_bf16(st[kh][b0i + 0], st[kh][b0i + 1]);
                        unsigned b  = cvtpk_bf16(st[kh][b0i + 4], st[kh][b0i + 5]);
                        unsigned a2 = cvtpk_bf16(st[kh][b0i + 2], st[kh][b0i + 3]);
                        unsigned b2 = cvtpk_bf16(st[kh][b0i + 6], st[kh][b0i + 7]);
                        plswap(a, b, lo_half);
                        plswap(a2, b2, lo_half);
                        u32x4 words = { a, a2, b, b2 };
                        pf[kh * 2 + hc] = __builtin_bit_cast(bf16x8, words);
                    }

#pragma unroll
                for (int dh = 0; dh < 2; ++dh) {
                    const int d = dh * 32 + ll;
                    const unsigned vsw = ((unsigned)((d ^ (d >> 4)) & 15)) << 4;
                    const unsigned vbb = (unsigned)(d * 256 + hi * 16);
#pragma unroll
                    for (int kc = 0; kc < 8; ++kc) {
                        const unsigned off = (vbb + (unsigned)(kc * 32)) ^ vsw;
                        const bf16x8 vfr = *reinterpret_cast<const bf16x8*>(Vcur + off);
                        oac[dh] = __builtin_amdgcn_mfma_f32_32x32x16_bf16(vfr, pf[kc], oac[dh], 0, 0, 0);
                    }
                }
            }

            if (notlast) writeV(cur ^ 1);
            __syncthreads();
            cur ^= 1;
        }

        const float inv = 1.0f / lsum;
        bf16_t* op = Og + (size_t)(sq * SEQLEN + q_glob) * E_DIM + h * 64;
#pragma unroll
        for (int dh = 0; dh < 2; ++dh)
#pragma unroll
            for (int rq = 0; rq < 4; ++rq) {
                const int d0 = dh * 32 + 8 * rq + 4 * hi;
                bf16x4 ov;
#pragma unroll
                for (int j = 0; j < 4; ++j)
                    ov[j] = (bf16_t)(oac[dh][rq * 4 + j] * inv);
                *reinterpret_cast<bf16x4*>(op + d0) = ov;
            }
    }
}

// ---------------------------------------------------------------------------
extern "C" void kernel_launch(void* const* d_in, const int* in_sizes, int n_in,
                              void* d_out, int out_size, void* d_ws, size_t ws_size,
                              hipStream_t stream) {
    const float* hid = (const float*)d_in[0];
    const float* Wq  = (const float*)d_in[1];
    const float* bq  = (const float*)d_in[2];
    const float* Wk  = (const float*)d_in[3];
    const float* bk  = (const float*)d_in[4];
    const float* Wv  = (const float*)d_in[5];
    const float* bv  = (const float*)d_in[6];
    const float* Wo  = (const float*)d_in[7];
    const float* bo  = (const float*)d_in[8];
    float* out = (float*)d_out;

    const size_t TE = (size_t)T_TOK * E_DIM;
    const size_t EE = (size_t)E_DIM * E_DIM;

    bf16_t* ws   = (bf16_t*)d_ws;
    bf16_t* hidB = ws;                 // later reused as attention output
    bf16_t* qkvB = ws + TE;            // [8192][6144]
    bf16_t* Wcat = qkvB + 3 * TE;      // [6144][2048] = Wq|Wk|Wv rows
    bf16_t* WoB  = Wcat + 3 * EE;

    cvt_f32_bf16<<<2048, 256, 0, stream>>>(hid, hidB, (int)(TE / 4));
    cvt_f32_bf16<<<1024, 256, 0, stream>>>(Wq, Wcat, (int)(EE / 4));
    cvt_f32_bf16<<<1024, 256, 0, stream>>>(Wk, Wcat + EE, (int)(EE / 4));
    cvt_f32_bf16<<<1024, 256, 0, stream>>>(Wv, Wcat + 2 * EE, (int)(EE / 4));
    cvt_f32_bf16<<<1024, 256, 0, stream>>>(Wo, WoB, (int)(EE / 4));

    // Q pre-scaled by D^-0.5 * log2(e): attention runs in exp2 domain.
    const float QSCALE = 0.125f * 1.4426950408889634f;

    gemm256<true><<<dim3((T_TOK / 256) * (LDQ / 256)), 512, 0, stream>>>(
        hidB, Wcat, bq, bk, bv, qkvB, T_TOK, LDQ, E_DIM, QSCALE, 2048);

    attn_fwd3<<<dim3(512), 512, 0, stream>>>(qkvB, hidB);

    gemm256<false><<<dim3((T_TOK / 256) * (E_DIM / 256)), 512, 0, stream>>>(
        hidB, WoB, bo, bo, bo, out, T_TOK, E_DIM, E_DIM, 1.0f, 0);
}

// Round 4
// 412.547 us; speedup vs baseline: 1.4536x; 1.0025x over previous
//
#include <hip/hip_runtime.h>
#include <hip/hip_bf16.h>

typedef __bf16 bf16_t;
typedef __bf16 bf16x8 __attribute__((ext_vector_type(8)));
typedef __bf16 bf16x4 __attribute__((ext_vector_type(4)));
typedef float f32x4 __attribute__((ext_vector_type(4)));
typedef float f32x16 __attribute__((ext_vector_type(16)));
typedef unsigned short u16x8 __attribute__((ext_vector_type(8)));
typedef unsigned int u32x4 __attribute__((ext_vector_type(4)));

#define T_TOK 8192
#define E_DIM 2048
#define NHEAD 32
#define SEQLEN 1024
#define NSEQ 8
#define LDQ 6144

#if __has_builtin(__builtin_amdgcn_exp2f)
#define EXP2F(x) __builtin_amdgcn_exp2f(x)
#else
#define EXP2F(x) exp2f(x)
#endif

static __device__ inline unsigned cvtpk_bf16(float lo, float hi) {
    unsigned r;
    asm("v_cvt_pk_bf16_f32 %0, %1, %2" : "=v"(r) : "v"(lo), "v"(hi));
    return r;
}

static __device__ inline void plswap(unsigned &x, unsigned &y, bool lo_half) {
#if __has_builtin(__builtin_amdgcn_permlane32_swap)
    auto r = __builtin_amdgcn_permlane32_swap(x, y, false, false);
    x = r[0]; y = r[1];
#else
    unsigned xs = __shfl_xor(x, 32), ys = __shfl_xor(y, 32);
    unsigned nx = lo_half ? x : ys;
    unsigned ny = lo_half ? xs : y;
    x = nx; y = ny;
#endif
}

// ---------------- fp32 -> bf16 conversion (vectorized, grid-stride) --------
__global__ void cvt_f32_bf16(const float* __restrict__ in, bf16_t* __restrict__ out, int n4) {
    int idx = blockIdx.x * blockDim.x + threadIdx.x;
    int stride = gridDim.x * blockDim.x;
    for (int i = idx; i < n4; i += stride) {
        const float4 v = reinterpret_cast<const float4*>(in)[i];
        bf16x4 o;
        o[0] = (bf16_t)v.x; o[1] = (bf16_t)v.y; o[2] = (bf16_t)v.z; o[3] = (bf16_t)v.w;
        reinterpret_cast<bf16x4*>(out)[i] = o;
    }
}

// ---------------- GEMM 256x256, BK=32, ring-4 slots, counted-vmcnt ---------
// C[M,N] = (A[M,K] * B[N,K]^T + bias) * (col<qlim ? qs : 1), K=2048 fixed.
// 8 waves (2M x 4N), per-wave 128x64. LDS 128KB: 4 slots x (A 16K + B 16K).
// Pipeline: tile t+3 staged during tile t (depth 3); tile-end wait vmcnt(8).
// Per tile: 2 phases x {ds_read; 2 gload_lds; bar; lgkm(0); prio1; 16 MFMA; prio0; bar}.
template<bool OUT_BF16>
__global__ __launch_bounds__(512, 2)
void gemm256p(const bf16_t* __restrict__ A, const bf16_t* __restrict__ B,
              const float* __restrict__ b0, const float* __restrict__ b1,
              const float* __restrict__ b2, void* __restrict__ Cout,
              int M, int N, float qs, int qlim) {
    constexpr int K = 2048;
    constexpr int NK = K / 32;   // 64
    __shared__ alignas(16) unsigned char lds[131072];
    const int tid = threadIdx.x;
    const int wid = tid >> 6, l = tid & 63;
    const int cpx = gridDim.x >> 3;           // grid divisible by 8
    const int wg = (blockIdx.x & 7) * cpx + (blockIdx.x >> 3);
    const int nbm = M >> 8;
    const int bm = wg % nbm, bn = wg / nbm;
    const int wrow = (wid >> 2) * 128, wcol = (wid & 3) * 64;
    const int lr = l & 15, lg = l >> 4;

    f32x4 acc[8][4] = {};

    const bf16_t* aBase = A + (size_t)(bm * 256) * K;
    const bf16_t* bBase = B + (size_t)(bn * 256) * K;
    const int sr = l >> 2;           // 0..15: row within 16-row chunk
    const int sc = (l & 3) * 16;     // byte col within 64B row

    auto stageA = [&](int t) {
        unsigned char* base = lds + (t & 3) * 32768;
#pragma unroll
        for (int c = 0; c < 2; ++c) {
            const int chunk = wid * 2 + c;
            const int r = chunk * 16 + sr;
            const int cb = sc ^ (((r >> 1) & 3) << 4);
            __builtin_amdgcn_global_load_lds(
                (const __attribute__((address_space(1))) void*)(aBase + (size_t)r * K + t * 32 + (cb >> 1)),
                (__attribute__((address_space(3))) void*)(base + chunk * 1024), 16, 0, 0);
        }
    };
    auto stageB = [&](int t) {
        unsigned char* base = lds + (t & 3) * 32768 + 16384;
#pragma unroll
        for (int c = 0; c < 2; ++c) {
            const int chunk = wid * 2 + c;
            const int r = chunk * 16 + sr;
            const int cb = sc ^ (((r >> 1) & 3) << 4);
            __builtin_amdgcn_global_load_lds(
                (const __attribute__((address_space(1))) void*)(bBase + (size_t)r * K + t * 32 + (cb >> 1)),
                (__attribute__((address_space(3))) void*)(base + chunk * 1024), 16, 0, 0);
        }
    };

    stageA(0); stageB(0); stageA(1); stageB(1); stageA(2); stageB(2);
    asm volatile("s_waitcnt vmcnt(8)" ::: "memory");   // tile 0 landed; 1,2 in flight
    __builtin_amdgcn_s_barrier();

    for (int t = 0; t < NK; ++t) {
        const unsigned char* Ab = lds + (t & 3) * 32768;
        const unsigned char* Bb = Ab + 16384;
        bf16x8 af[8], bfv[4];
        // ---------- phase 0: m 0..3 ----------
#pragma unroll
        for (int m = 0; m < 4; ++m) {
            const int r = wrow + m * 16 + lr;
            af[m] = *reinterpret_cast<const bf16x8*>(Ab + r * 64 + ((lg * 16) ^ (((r >> 1) & 3) << 4)));
        }
#pragma unroll
        for (int n = 0; n < 4; ++n) {
            const int r = wcol + n * 16 + lr;
            bfv[n] = *reinterpret_cast<const bf16x8*>(Bb + r * 64 + ((lg * 16) ^ (((r >> 1) & 3) << 4)));
        }
        if (t + 3 < NK) stageA(t + 3);
        __builtin_amdgcn_s_barrier();
        asm volatile("s_waitcnt lgkmcnt(0)" ::: "memory");
        __builtin_amdgcn_sched_barrier(0);
        __builtin_amdgcn_s_setprio(1);
#pragma unroll
        for (int m = 0; m < 4; ++m)
#pragma unroll
            for (int n = 0; n < 4; ++n)
                acc[m][n] = __builtin_amdgcn_mfma_f32_16x16x32_bf16(af[m], bfv[n], acc[m][n], 0, 0, 0);
        __builtin_amdgcn_s_setprio(0);
        __builtin_amdgcn_s_barrier();
        // ---------- phase 1: m 4..7 ----------
#pragma unroll
        for (int m = 4; m < 8; ++m) {
            const int r = wrow + m * 16 + lr;
            af[m] = *reinterpret_cast<const bf16x8*>(Ab + r * 64 + ((lg * 16) ^ (((r >> 1) & 3) << 4)));
        }
        if (t + 3 < NK) stageB(t + 3);
        __builtin_amdgcn_s_barrier();
        asm volatile("s_waitcnt lgkmcnt(0)" ::: "memory");
        __builtin_amdgcn_sched_barrier(0);
        __builtin_amdgcn_s_setprio(1);
#pragma unroll
        for (int m = 4; m < 8; ++m)
#pragma unroll
            for (int n = 0; n < 4; ++n)
                acc[m][n] = __builtin_amdgcn_mfma_f32_16x16x32_bf16(af[m], bfv[n], acc[m][n], 0, 0, 0);
        __builtin_amdgcn_s_setprio(0);
        if (t == NK - 1) break;
        if (t <= NK - 4)      asm volatile("s_waitcnt vmcnt(8)" ::: "memory");  // t+1 landed; t+2,t+3 in flight
        else if (t == NK - 3) asm volatile("s_waitcnt vmcnt(4)" ::: "memory");
        else                  asm volatile("s_waitcnt vmcnt(0)" ::: "memory");
        __builtin_amdgcn_s_barrier();
    }

    // epilogue: C[row=(l>>4)*4+j][col=l&15] per fragment
    const int r0 = bm * 256 + wrow + lg * 4;
    const int c0 = bn * 256 + wcol + lr;
#pragma unroll
    for (int n = 0; n < 4; ++n) {
        const int cc = c0 + n * 16;
        const float bias = (cc < 2048) ? b0[cc] : (cc < 4096 ? b1[cc - 2048] : b2[cc - 4096]);
        const float sc2 = (cc < qlim) ? qs : 1.0f;
#pragma unroll
        for (int m = 0; m < 8; ++m)
#pragma unroll
            for (int j = 0; j < 4; ++j) {
                const int rr = r0 + m * 16 + j;
                const float v = (acc[m][n][j] + bias) * sc2;
                if (OUT_BF16) ((bf16_t*)Cout)[(size_t)rr * N + cc] = (bf16_t)v;
                else          ((float*)Cout)[(size_t)rr * N + cc] = v;
            }
    }
}

// ---------------- Flash attention, 8-wave 32x32 swapped-QK^T, paired qt ----
__global__ __launch_bounds__(512, 2)
void attn_fwd3(const bf16_t* __restrict__ QKV, bf16_t* __restrict__ Og) {
    const int orig = blockIdx.x;               // 0..511
    const int id = (orig & 7) * 64 + (orig >> 3);
    const int grp = id >> 1;                   // (h, sq)
    const int pairIdx = id & 1;
    const int h = grp & 31;
    const int sq = grp >> 5;

    const int tid = threadIdx.x;
    const int w = tid >> 6;
    const int l = tid & 63;
    const int ll = l & 31;
    const int hi = l >> 5;
    const bool lo_half = (hi == 0);

    __shared__ alignas(16) unsigned char lds[65536];  // K[2][16KB] + V[2][16KB]

    const bf16_t* Qg = QKV;
    const bf16_t* Kg = QKV + 2048;
    const bf16_t* Vg = QKV + 4096;
    const size_t kvbase = (size_t)(sq * SEQLEN) * LDQ + h * 64;

    bf16x8 vr0, vr1;
    const int vk0 = l * 2;
    const int vd0 = w * 8;

    auto stageK = [&](int kt, int buf) {
#pragma unroll
        for (int c = 0; c < 2; ++c) {
            const int o = (w * 2 + c) * 1024 + l * 16;
            const int r = o >> 7;
            const int swb = (o & 127) ^ ((r & 7) << 4);
            const bf16_t* src = Kg + kvbase + (size_t)(kt * 128 + r) * LDQ + (swb >> 1);
            __builtin_amdgcn_global_load_lds(
                (const __attribute__((address_space(1))) void*)src,
                (__attribute__((address_space(3))) void*)(lds + buf * 16384 + (w * 2 + c) * 1024),
                16, 0, 0);
        }
    };
    auto loadV = [&](int kt) {
        const bf16_t* vp = Vg + kvbase + (size_t)(kt * 128 + vk0) * LDQ + vd0;
        vr0 = *reinterpret_cast<const bf16x8*>(vp);
        vr1 = *reinterpret_cast<const bf16x8*>(vp + LDQ);
    };
    auto writeV = [&](int buf) {
        u16x8 s0 = __builtin_bit_cast(u16x8, vr0);
        u16x8 s1 = __builtin_bit_cast(u16x8, vr1);
        unsigned char* vb = lds + 32768 + buf * 16384;
#pragma unroll
        for (int e = 0; e < 8; ++e) {
            const int d = vd0 + e;
            unsigned off = (unsigned)(d * 256 + vk0 * 2);
            off ^= ((unsigned)((d ^ (d >> 4)) & 15)) << 4;
            *reinterpret_cast<unsigned*>(vb + off) = (unsigned)s0[e] | ((unsigned)s1[e] << 16);
        }
    };

    const unsigned ksw = (unsigned)((l & 7) << 4);
    const unsigned kbase = (unsigned)(ll * 128 + hi * 16);

#pragma unroll 1
    for (int seg = 0; seg < 2; ++seg) {
        const int qt = pairIdx ? (seg ? 2 : 1) : (seg ? 3 : 0);

        const int q_glob = qt * 256 + w * 32 + ll;
        const bf16_t* qp = Qg + (size_t)(sq * SEQLEN + q_glob) * LDQ + h * 64 + hi * 8;
        bf16x8 qf[4];
#pragma unroll
        for (int dc = 0; dc < 4; ++dc)
            qf[dc] = *reinterpret_cast<const bf16x8*>(qp + dc * 16);

        const int nkt = 2 * qt + 2;
        const int q_wave_max = qt * 256 + w * 32 + 31;

        f32x16 oac[2] = {};
        float mrun = -3.0e38f, lsum = 0.f;

        stageK(0, 0);
        loadV(0);
        writeV(0);
        __syncthreads();

        int cur = 0;
        for (int kt = 0; kt < nkt; ++kt) {
            const bool notlast = (kt + 1 < nkt);
            if (notlast) { stageK(kt + 1, cur ^ 1); loadV(kt + 1); }

            if (kt * 128 <= q_wave_max) {
                const unsigned char* Kcur = lds + cur * 16384;
                const unsigned char* Vcur = lds + 32768 + cur * 16384;

                f32x16 st[4];
#pragma unroll
                for (int kh = 0; kh < 4; ++kh) {
                    f32x16 acc = {};
#pragma unroll
                    for (int dc = 0; dc < 4; ++dc) {
                        const unsigned off = (kbase + (unsigned)(kh * 4096 + dc * 32)) ^ ksw;
                        const bf16x8 ka = *reinterpret_cast<const bf16x8*>(Kcur + off);
                        acc = __builtin_amdgcn_mfma_f32_32x32x16_bf16(ka, qf[dc], acc, 0, 0, 0);
                    }
                    st[kh] = acc;
                }

                if (kt >= 2 * qt) {
#pragma unroll
                    for (int kh = 0; kh < 4; ++kh)
#pragma unroll
                        for (int r = 0; r < 16; ++r) {
                            const int kg = kt * 128 + kh * 32 + (r & 3) + 8 * (r >> 2) + 4 * hi;
                            if (kg > q_glob) st[kh][r] = -3.0e38f;
                        }
                }

                float tm = -3.0e38f;
#pragma unroll
                for (int kh = 0; kh < 4; ++kh)
#pragma unroll
                    for (int r = 0; r < 16; ++r) tm = fmaxf(tm, st[kh][r]);
                tm = fmaxf(tm, __shfl_xor(tm, 32));

                if (!__all(tm <= mrun + 8.0f)) {
                    const float mnew = fmaxf(mrun, tm);
                    const float rsc = EXP2F(mrun - mnew);
                    mrun = mnew;
                    lsum *= rsc;
#pragma unroll
                    for (int dh = 0; dh < 2; ++dh)
#pragma unroll
                        for (int r = 0; r < 16; ++r) oac[dh][r] *= rsc;
                }

                float ps = 0.f;
#pragma unroll
                for (int kh = 0; kh < 4; ++kh)
#pragma unroll
                    for (int r = 0; r < 16; ++r) {
                        const float p = EXP2F(st[kh][r] - mrun);
                        st[kh][r] = p;
                        ps += p;
                    }
                ps += __shfl_xor(ps, 32);
                lsum += ps;

                bf16x8 pf[8];
#pragma unroll
                for (int kh = 0; kh < 4; ++kh)
#pragma unroll
                    for (int hc = 0; hc < 2; ++hc) {
                        const int b0i = hc * 8;
                        unsigned a  = cvtpk_bf16(st[kh][b0i + 0], st[kh][b0i + 1]);
                        unsigned b  = cvtpk_bf16(st[kh][b0i + 4], st[kh][b0i + 5]);
                        unsigned a2 = cvtpk_bf16(st[kh][b0i + 2], st[kh][b0i + 3]);
                        unsigned b2 = cvtpk_bf16(st[kh][b0i + 6], st[kh][b0i + 7]);
                        plswap(a, b, lo_half);
                        plswap(a2, b2, lo_half);
                        u32x4 words = { a, a2, b, b2 };
                        pf[kh * 2 + hc] = __builtin_bit_cast(bf16x8, words);
                    }

#pragma unroll
                for (int dh = 0; dh < 2; ++dh) {
                    const int d = dh * 32 + ll;
                    const unsigned vsw = ((unsigned)((d ^ (d >> 4)) & 15)) << 4;
                    const unsigned vbb = (unsigned)(d * 256 + hi * 16);
#pragma unroll
                    for (int kc = 0; kc < 8; ++kc) {
                        const unsigned off = (vbb + (unsigned)(kc * 32)) ^ vsw;
                        const bf16x8 vfr = *reinterpret_cast<const bf16x8*>(Vcur + off);
                        oac[dh] = __builtin_amdgcn_mfma_f32_32x32x16_bf16(vfr, pf[kc], oac[dh], 0, 0, 0);
                    }
                }
            }

            if (notlast) writeV(cur ^ 1);
            __syncthreads();
            cur ^= 1;
        }

        const float inv = 1.0f / lsum;
        bf16_t* op = Og + (size_t)(sq * SEQLEN + q_glob) * E_DIM + h * 64;
#pragma unroll
        for (int dh = 0; dh < 2; ++dh)
#pragma unroll
            for (int rq = 0; rq < 4; ++rq) {
                const int d0 = dh * 32 + 8 * rq + 4 * hi;
                bf16x4 ov;
#pragma unroll
                for (int j = 0; j < 4; ++j)
                    ov[j] = (bf16_t)(oac[dh][rq * 4 + j] * inv);
                *reinterpret_cast<bf16x4*>(op + d0) = ov;
            }
    }
}

// ---------------------------------------------------------------------------
extern "C" void kernel_launch(void* const* d_in, const int* in_sizes, int n_in,
                              void* d_out, int out_size, void* d_ws, size_t ws_size,
                              hipStream_t stream) {
    const float* hid = (const float*)d_in[0];
    const float* Wq  = (const float*)d_in[1];
    const float* bq  = (const float*)d_in[2];
    const float* Wk  = (const float*)d_in[3];
    const float* bk  = (const float*)d_in[4];
    const float* Wv  = (const float*)d_in[5];
    const float* bv  = (const float*)d_in[6];
    const float* Wo  = (const float*)d_in[7];
    const float* bo  = (const float*)d_in[8];
    float* out = (float*)d_out;

    const size_t TE = (size_t)T_TOK * E_DIM;
    const size_t EE = (size_t)E_DIM * E_DIM;

    bf16_t* ws   = (bf16_t*)d_ws;
    bf16_t* hidB = ws;                 // later reused as attention output
    bf16_t* qkvB = ws + TE;            // [8192][6144]
    bf16_t* Wcat = qkvB + 3 * TE;      // [6144][2048] = Wq|Wk|Wv rows
    bf16_t* WoB  = Wcat + 3 * EE;

    cvt_f32_bf16<<<2048, 256, 0, stream>>>(hid, hidB, (int)(TE / 4));
    cvt_f32_bf16<<<1024, 256, 0, stream>>>(Wq, Wcat, (int)(EE / 4));
    cvt_f32_bf16<<<1024, 256, 0, stream>>>(Wk, Wcat + EE, (int)(EE / 4));
    cvt_f32_bf16<<<1024, 256, 0, stream>>>(Wv, Wcat + 2 * EE, (int)(EE / 4));
    cvt_f32_bf16<<<1024, 256, 0, stream>>>(Wo, WoB, (int)(EE / 4));

    // Q pre-scaled by D^-0.5 * log2(e): attention runs in exp2 domain.
    const float QSCALE = 0.125f * 1.4426950408889634f;

    gemm256p<true><<<dim3((T_TOK / 256) * (LDQ / 256)), 512, 0, stream>>>(
        hidB, Wcat, bq, bk, bv, qkvB, T_TOK, LDQ, QSCALE, 2048);

    attn_fwd3<<<dim3(512), 512, 0, stream>>>(qkvB, hidB);

    gemm256p<false><<<dim3((T_TOK / 256) * (E_DIM / 256)), 512, 0, stream>>>(
        hidB, WoB, bo, bo, bo, out, T_TOK, E_DIM, 1.0f, 0);
}

// Round 5
// 410.418 us; speedup vs baseline: 1.4611x; 1.0052x over previous
//
#include <hip/hip_runtime.h>
#include <hip/hip_bf16.h>

typedef __bf16 bf16_t;
typedef __bf16 bf16x8 __attribute__((ext_vector_type(8)));
typedef __bf16 bf16x4 __attribute__((ext_vector_type(4)));
typedef float f32x4 __attribute__((ext_vector_type(4)));
typedef float f32x16 __attribute__((ext_vector_type(16)));
typedef unsigned short u16x8 __attribute__((ext_vector_type(8)));
typedef unsigned int u32x4 __attribute__((ext_vector_type(4)));

#define T_TOK 8192
#define E_DIM 2048
#define NHEAD 32
#define SEQLEN 1024
#define NSEQ 8
#define LDQ 6144

#if __has_builtin(__builtin_amdgcn_exp2f)
#define EXP2F(x) __builtin_amdgcn_exp2f(x)
#else
#define EXP2F(x) exp2f(x)
#endif

static __device__ inline unsigned cvtpk_bf16(float lo, float hi) {
    unsigned r;
    asm("v_cvt_pk_bf16_f32 %0, %1, %2" : "=v"(r) : "v"(lo), "v"(hi));
    return r;
}

static __device__ inline void plswap(unsigned &x, unsigned &y, bool lo_half) {
#if __has_builtin(__builtin_amdgcn_permlane32_swap)
    auto r = __builtin_amdgcn_permlane32_swap(x, y, false, false);
    x = r[0]; y = r[1];
#else
    unsigned xs = __shfl_xor(x, 32), ys = __shfl_xor(y, 32);
    unsigned nx = lo_half ? x : ys;
    unsigned ny = lo_half ? xs : y;
    x = nx; y = ny;
#endif
}

// ---------------- fp32 -> bf16 conversion (vectorized, grid-stride) --------
__global__ void cvt_f32_bf16(const float* __restrict__ in, bf16_t* __restrict__ out, int n4) {
    int idx = blockIdx.x * blockDim.x + threadIdx.x;
    int stride = gridDim.x * blockDim.x;
    for (int i = idx; i < n4; i += stride) {
        const float4 v = reinterpret_cast<const float4*>(in)[i];
        bf16x4 o;
        o[0] = (bf16_t)v.x; o[1] = (bf16_t)v.y; o[2] = (bf16_t)v.z; o[3] = (bf16_t)v.w;
        reinterpret_cast<bf16x4*>(out)[i] = o;
    }
}

// ---------------- GEMM 256x256, BK=32, ring-4, compiler-scheduled waits ----
// C[M,N] = (A[M,K] * B[N,K]^T + bias) * (col<qlim ? qs : 1), K=2048 fixed.
// 8 waves (2M x 4N), per-wave 128x64. LDS 128KB: 4 slots x (A 16K + B 16K).
// Per tile: {stage(t+3); 12 plain ds_reads; 32 MFMA (compiler inserts
// fine-grained lgkmcnt so MFMA overlaps LDS service); vmcnt(8); s_barrier}.
// ONE barrier per K-tile. No lgkmcnt(0) drain, no sched_barrier(0).
template<bool OUT_BF16>
__global__ __launch_bounds__(512, 2)
void gemm256r(const bf16_t* __restrict__ A, const bf16_t* __restrict__ B,
              const float* __restrict__ b0, const float* __restrict__ b1,
              const float* __restrict__ b2, void* __restrict__ Cout,
              int M, int N, float qs, int qlim) {
    constexpr int K = 2048;
    constexpr int NK = K / 32;   // 64
    __shared__ alignas(16) unsigned char lds[131072];
    const int tid = threadIdx.x;
    const int wid = tid >> 6, l = tid & 63;
    const int cpx = gridDim.x >> 3;           // grid divisible by 8
    const int wg = (blockIdx.x & 7) * cpx + (blockIdx.x >> 3);
    const int nbm = M >> 8;
    const int bm = wg % nbm, bn = wg / nbm;
    const int wrow = (wid >> 2) * 128, wcol = (wid & 3) * 64;
    const int lr = l & 15, lg = l >> 4;

    f32x4 acc[8][4] = {};

    const bf16_t* aBase = A + (size_t)(bm * 256) * K;
    const bf16_t* bBase = B + (size_t)(bn * 256) * K;
    const int sr = l >> 2;           // 0..15: row within 16-row chunk
    const int sc = (l & 3) * 16;     // byte col within 64B row

    auto stage = [&](int t) {
        unsigned char* base = lds + (t & 3) * 32768;
#pragma unroll
        for (int c = 0; c < 2; ++c) {
            const int chunk = wid * 2 + c;
            const int r = chunk * 16 + sr;
            const int cb = sc ^ (((r >> 1) & 3) << 4);
            __builtin_amdgcn_global_load_lds(
                (const __attribute__((address_space(1))) void*)(aBase + (size_t)r * K + t * 32 + (cb >> 1)),
                (__attribute__((address_space(3))) void*)(base + chunk * 1024), 16, 0, 0);
            __builtin_amdgcn_global_load_lds(
                (const __attribute__((address_space(1))) void*)(bBase + (size_t)r * K + t * 32 + (cb >> 1)),
                (__attribute__((address_space(3))) void*)(base + 16384 + chunk * 1024), 16, 0, 0);
        }
    };

    stage(0); stage(1); stage(2);
    asm volatile("s_waitcnt vmcnt(8)" ::: "memory");   // tile 0 landed; 1,2 in flight
    __builtin_amdgcn_s_barrier();

    for (int t = 0; t < NK; ++t) {
        if (t + 3 < NK) stage(t + 3);                  // slot (t+3)&3 == (t-1)&3, dead
        const unsigned char* Ab = lds + (t & 3) * 32768;
        const unsigned char* Bb = Ab + 16384;
        bf16x8 bfv[4], af[8];
#pragma unroll
        for (int n = 0; n < 4; ++n) {
            const int r = wcol + n * 16 + lr;
            bfv[n] = *reinterpret_cast<const bf16x8*>(Bb + r * 64 + ((lg * 16) ^ (((r >> 1) & 3) << 4)));
        }
#pragma unroll
        for (int m = 0; m < 8; ++m) {
            const int r = wrow + m * 16 + lr;
            af[m] = *reinterpret_cast<const bf16x8*>(Ab + r * 64 + ((lg * 16) ^ (((r >> 1) & 3) << 4)));
        }
        __builtin_amdgcn_s_setprio(1);
#pragma unroll
        for (int m = 0; m < 8; ++m)
#pragma unroll
            for (int n = 0; n < 4; ++n)
                acc[m][n] = __builtin_amdgcn_mfma_f32_16x16x32_bf16(af[m], bfv[n], acc[m][n], 0, 0, 0);
        __builtin_amdgcn_s_setprio(0);
        if (t == NK - 1) break;
        if (t + 3 < NK)      asm volatile("s_waitcnt vmcnt(8)" ::: "memory");  // t+1 landed
        else if (t + 2 < NK) asm volatile("s_waitcnt vmcnt(4)" ::: "memory");
        else                 asm volatile("s_waitcnt vmcnt(0)" ::: "memory");
        __builtin_amdgcn_s_barrier();
    }

    // epilogue: C[row=(l>>4)*4+j][col=l&15] per fragment
    const int r0 = bm * 256 + wrow + lg * 4;
    const int c0 = bn * 256 + wcol + lr;
#pragma unroll
    for (int n = 0; n < 4; ++n) {
        const int cc = c0 + n * 16;
        const float bias = (cc < 2048) ? b0[cc] : (cc < 4096 ? b1[cc - 2048] : b2[cc - 4096]);
        const float sc2 = (cc < qlim) ? qs : 1.0f;
#pragma unroll
        for (int m = 0; m < 8; ++m)
#pragma unroll
            for (int j = 0; j < 4; ++j) {
                const int rr = r0 + m * 16 + j;
                const float v = (acc[m][n][j] + bias) * sc2;
                if (OUT_BF16) ((bf16_t*)Cout)[(size_t)rr * N + cc] = (bf16_t)v;
                else          ((float*)Cout)[(size_t)rr * N + cc] = v;
            }
    }
}

// ---------------- Flash attention, 8-wave 32x32 swapped-QK^T, paired qt ----
__global__ __launch_bounds__(512, 2)
void attn_fwd3(const bf16_t* __restrict__ QKV, bf16_t* __restrict__ Og) {
    const int orig = blockIdx.x;               // 0..511
    const int id = (orig & 7) * 64 + (orig >> 3);
    const int grp = id >> 1;                   // (h, sq)
    const int pairIdx = id & 1;
    const int h = grp & 31;
    const int sq = grp >> 5;

    const int tid = threadIdx.x;
    const int w = tid >> 6;
    const int l = tid & 63;
    const int ll = l & 31;
    const int hi = l >> 5;
    const bool lo_half = (hi == 0);

    __shared__ alignas(16) unsigned char lds[65536];  // K[2][16KB] + V[2][16KB]

    const bf16_t* Qg = QKV;
    const bf16_t* Kg = QKV + 2048;
    const bf16_t* Vg = QKV + 4096;
    const size_t kvbase = (size_t)(sq * SEQLEN) * LDQ + h * 64;

    bf16x8 vr0, vr1;
    const int vk0 = l * 2;
    const int vd0 = w * 8;

    auto stageK = [&](int kt, int buf) {
#pragma unroll
        for (int c = 0; c < 2; ++c) {
            const int o = (w * 2 + c) * 1024 + l * 16;
            const int r = o >> 7;
            const int swb = (o & 127) ^ ((r & 7) << 4);
            const bf16_t* src = Kg + kvbase + (size_t)(kt * 128 + r) * LDQ + (swb >> 1);
            __builtin_amdgcn_global_load_lds(
                (const __attribute__((address_space(1))) void*)src,
                (__attribute__((address_space(3))) void*)(lds + buf * 16384 + (w * 2 + c) * 1024),
                16, 0, 0);
        }
    };
    auto loadV = [&](int kt) {
        const bf16_t* vp = Vg + kvbase + (size_t)(kt * 128 + vk0) * LDQ + vd0;
        vr0 = *reinterpret_cast<const bf16x8*>(vp);
        vr1 = *reinterpret_cast<const bf16x8*>(vp + LDQ);
    };
    auto writeV = [&](int buf) {
        u16x8 s0 = __builtin_bit_cast(u16x8, vr0);
        u16x8 s1 = __builtin_bit_cast(u16x8, vr1);
        unsigned char* vb = lds + 32768 + buf * 16384;
#pragma unroll
        for (int e = 0; e < 8; ++e) {
            const int d = vd0 + e;
            unsigned off = (unsigned)(d * 256 + vk0 * 2);
            off ^= ((unsigned)((d ^ (d >> 4)) & 15)) << 4;
            *reinterpret_cast<unsigned*>(vb + off) = (unsigned)s0[e] | ((unsigned)s1[e] << 16);
        }
    };

    const unsigned ksw = (unsigned)((l & 7) << 4);
    const unsigned kbase = (unsigned)(ll * 128 + hi * 16);

#pragma unroll 1
    for (int seg = 0; seg < 2; ++seg) {
        const int qt = pairIdx ? (seg ? 2 : 1) : (seg ? 3 : 0);

        const int q_glob = qt * 256 + w * 32 + ll;
        const bf16_t* qp = Qg + (size_t)(sq * SEQLEN + q_glob) * LDQ + h * 64 + hi * 8;
        bf16x8 qf[4];
#pragma unroll
        for (int dc = 0; dc < 4; ++dc)
            qf[dc] = *reinterpret_cast<const bf16x8*>(qp + dc * 16);

        const int nkt = 2 * qt + 2;
        const int q_wave_max = qt * 256 + w * 32 + 31;

        f32x16 oac[2] = {};
        float mrun = -3.0e38f, lsum = 0.f;

        stageK(0, 0);
        loadV(0);
        writeV(0);
        __syncthreads();

        int cur = 0;
        for (int kt = 0; kt < nkt; ++kt) {
            const bool notlast = (kt + 1 < nkt);
            if (notlast) { stageK(kt + 1, cur ^ 1); loadV(kt + 1); }

            if (kt * 128 <= q_wave_max) {
                const unsigned char* Kcur = lds + cur * 16384;
                const unsigned char* Vcur = lds + 32768 + cur * 16384;

                f32x16 st[4];
#pragma unroll
                for (int kh = 0; kh < 4; ++kh) {
                    f32x16 acc = {};
#pragma unroll
                    for (int dc = 0; dc < 4; ++dc) {
                        const unsigned off = (kbase + (unsigned)(kh * 4096 + dc * 32)) ^ ksw;
                        const bf16x8 ka = *reinterpret_cast<const bf16x8*>(Kcur + off);
                        acc = __builtin_amdgcn_mfma_f32_32x32x16_bf16(ka, qf[dc], acc, 0, 0, 0);
                    }
                    st[kh] = acc;
                }

                if (kt >= 2 * qt) {
#pragma unroll
                    for (int kh = 0; kh < 4; ++kh)
#pragma unroll
                        for (int r = 0; r < 16; ++r) {
                            const int kg = kt * 128 + kh * 32 + (r & 3) + 8 * (r >> 2) + 4 * hi;
                            if (kg > q_glob) st[kh][r] = -3.0e38f;
                        }
                }

                float tm = -3.0e38f;
#pragma unroll
                for (int kh = 0; kh < 4; ++kh)
#pragma unroll
                    for (int r = 0; r < 16; ++r) tm = fmaxf(tm, st[kh][r]);
                tm = fmaxf(tm, __shfl_xor(tm, 32));

                if (!__all(tm <= mrun + 8.0f)) {
                    const float mnew = fmaxf(mrun, tm);
                    const float rsc = EXP2F(mrun - mnew);
                    mrun = mnew;
                    lsum *= rsc;
#pragma unroll
                    for (int dh = 0; dh < 2; ++dh)
#pragma unroll
                        for (int r = 0; r < 16; ++r) oac[dh][r] *= rsc;
                }

                float ps = 0.f;
#pragma unroll
                for (int kh = 0; kh < 4; ++kh)
#pragma unroll
                    for (int r = 0; r < 16; ++r) {
                        const float p = EXP2F(st[kh][r] - mrun);
                        st[kh][r] = p;
                        ps += p;
                    }
                ps += __shfl_xor(ps, 32);
                lsum += ps;

                bf16x8 pf[8];
#pragma unroll
                for (int kh = 0; kh < 4; ++kh)
#pragma unroll
                    for (int hc = 0; hc < 2; ++hc) {
                        const int b0i = hc * 8;
                        unsigned a  = cvtpk_bf16(st[kh][b0i + 0], st[kh][b0i + 1]);
                        unsigned b  = cvtpk_bf16(st[kh][b0i + 4], st[kh][b0i + 5]);
                        unsigned a2 = cvtpk_bf16(st[kh][b0i + 2], st[kh][b0i + 3]);
                        unsigned b2 = cvtpk_bf16(st[kh][b0i + 6], st[kh][b0i + 7]);
                        plswap(a, b, lo_half);
                        plswap(a2, b2, lo_half);
                        u32x4 words = { a, a2, b, b2 };
                        pf[kh * 2 + hc] = __builtin_bit_cast(bf16x8, words);
                    }

#pragma unroll
                for (int dh = 0; dh < 2; ++dh) {
                    const int d = dh * 32 + ll;
                    const unsigned vsw = ((unsigned)((d ^ (d >> 4)) & 15)) << 4;
                    const unsigned vbb = (unsigned)(d * 256 + hi * 16);
#pragma unroll
                    for (int kc = 0; kc < 8; ++kc) {
                        const unsigned off = (vbb + (unsigned)(kc * 32)) ^ vsw;
                        const bf16x8 vfr = *reinterpret_cast<const bf16x8*>(Vcur + off);
                        oac[dh] = __builtin_amdgcn_mfma_f32_32x32x16_bf16(vfr, pf[kc], oac[dh], 0, 0, 0);
                    }
                }
            }

            if (notlast) writeV(cur ^ 1);
            __syncthreads();
            cur ^= 1;
        }

        const float inv = 1.0f / lsum;
        bf16_t* op = Og + (size_t)(sq * SEQLEN + q_glob) * E_DIM + h * 64;
#pragma unroll
        for (int dh = 0; dh < 2; ++dh)
#pragma unroll
            for (int rq = 0; rq < 4; ++rq) {
                const int d0 = dh * 32 + 8 * rq + 4 * hi;
                bf16x4 ov;
#pragma unroll
                for (int j = 0; j < 4; ++j)
                    ov[j] = (bf16_t)(oac[dh][rq * 4 + j] * inv);
                *reinterpret_cast<bf16x4*>(op + d0) = ov;
            }
    }
}

// ---------------------------------------------------------------------------
extern "C" void kernel_launch(void* const* d_in, const int* in_sizes, int n_in,
                              void* d_out, int out_size, void* d_ws, size_t ws_size,
                              hipStream_t stream) {
    const float* hid = (const float*)d_in[0];
    const float* Wq  = (const float*)d_in[1];
    const float* bq  = (const float*)d_in[2];
    const float* Wk  = (const float*)d_in[3];
    const float* bk  = (const float*)d_in[4];
    const float* Wv  = (const float*)d_in[5];
    const float* bv  = (const float*)d_in[6];
    const float* Wo  = (const float*)d_in[7];
    const float* bo  = (const float*)d_in[8];
    float* out = (float*)d_out;

    const size_t TE = (size_t)T_TOK * E_DIM;
    const size_t EE = (size_t)E_DIM * E_DIM;

    bf16_t* ws   = (bf16_t*)d_ws;
    bf16_t* hidB = ws;                 // later reused as attention output
    bf16_t* qkvB = ws + TE;            // [8192][6144]
    bf16_t* Wcat = qkvB + 3 * TE;      // [6144][2048] = Wq|Wk|Wv rows
    bf16_t* WoB  = Wcat + 3 * EE;

    cvt_f32_bf16<<<2048, 256, 0, stream>>>(hid, hidB, (int)(TE / 4));
    cvt_f32_bf16<<<1024, 256, 0, stream>>>(Wq, Wcat, (int)(EE / 4));
    cvt_f32_bf16<<<1024, 256, 0, stream>>>(Wk, Wcat + EE, (int)(EE / 4));
    cvt_f32_bf16<<<1024, 256, 0, stream>>>(Wv, Wcat + 2 * EE, (int)(EE / 4));
    cvt_f32_bf16<<<1024, 256, 0, stream>>>(Wo, WoB, (int)(EE / 4));

    // Q pre-scaled by D^-0.5 * log2(e): attention runs in exp2 domain.
    const float QSCALE = 0.125f * 1.4426950408889634f;

    gemm256r<true><<<dim3((T_TOK / 256) * (LDQ / 256)), 512, 0, stream>>>(
        hidB, Wcat, bq, bk, bv, qkvB, T_TOK, LDQ, QSCALE, 2048);

    attn_fwd3<<<dim3(512), 512, 0, stream>>>(qkvB, hidB);

    gemm256r<false><<<dim3((T_TOK / 256) * (E_DIM / 256)), 512, 0, stream>>>(
        hidB, WoB, bo, bo, bo, out, T_TOK, E_DIM, 1.0f, 0);
}

// Round 6
// 397.905 us; speedup vs baseline: 1.5071x; 1.0314x over previous
//
#include <hip/hip_runtime.h>
#include <hip/hip_bf16.h>

typedef __bf16 bf16_t;
typedef __bf16 bf16x8 __attribute__((ext_vector_type(8)));
typedef __bf16 bf16x4 __attribute__((ext_vector_type(4)));
typedef float f32x4 __attribute__((ext_vector_type(4)));
typedef float f32x16 __attribute__((ext_vector_type(16)));
typedef unsigned short u16x8 __attribute__((ext_vector_type(8)));
typedef unsigned int u32x4 __attribute__((ext_vector_type(4)));

#define T_TOK 8192
#define E_DIM 2048
#define NHEAD 32
#define SEQLEN 1024
#define NSEQ 8
#define LDQ 6144

#if __has_builtin(__builtin_amdgcn_exp2f)
#define EXP2F(x) __builtin_amdgcn_exp2f(x)
#else
#define EXP2F(x) exp2f(x)
#endif

static __device__ inline unsigned cvtpk_bf16(float lo, float hi) {
    unsigned r;
    asm("v_cvt_pk_bf16_f32 %0, %1, %2" : "=v"(r) : "v"(lo), "v"(hi));
    return r;
}

static __device__ inline void plswap(unsigned &x, unsigned &y, bool lo_half) {
#if __has_builtin(__builtin_amdgcn_permlane32_swap)
    auto r = __builtin_amdgcn_permlane32_swap(x, y, false, false);
    x = r[0]; y = r[1];
#else
    unsigned xs = __shfl_xor(x, 32), ys = __shfl_xor(y, 32);
    unsigned nx = lo_half ? x : ys;
    unsigned ny = lo_half ? xs : y;
    x = nx; y = ny;
#endif
}

// ---------------- fused fp32 -> bf16 conversion (5 regions, 1 launch) ------
__global__ void cvt_all(const float* __restrict__ hid, const float* __restrict__ Wq,
                        const float* __restrict__ Wk, const float* __restrict__ Wv,
                        const float* __restrict__ Wo, bf16_t* __restrict__ hidB,
                        bf16_t* __restrict__ Wcat, bf16_t* __restrict__ WoB) {
    const int TE4 = (T_TOK * E_DIM) / 4;      // 4M float4 groups
    const int EE4 = (E_DIM * E_DIM) / 4;      // 1M
    const float* src;
    bf16_t* dst;
    int n4, base, nb;
    const int bid = blockIdx.x;
    if (bid < 2048)      { src = hid; dst = hidB;              n4 = TE4; base = 0;    nb = 2048; }
    else if (bid < 2560) { src = Wq;  dst = Wcat;              n4 = EE4; base = 2048; nb = 512; }
    else if (bid < 3072) { src = Wk;  dst = Wcat + 4 * EE4;    n4 = EE4; base = 2560; nb = 512; }
    else if (bid < 3584) { src = Wv;  dst = Wcat + 8 * EE4;    n4 = EE4; base = 3072; nb = 512; }
    else                 { src = Wo;  dst = WoB;               n4 = EE4; base = 3584; nb = 512; }
    const int stride = nb * 256;
    for (int i = (bid - base) * 256 + threadIdx.x; i < n4; i += stride) {
        const float4 v = reinterpret_cast<const float4*>(src)[i];
        bf16x4 o;
        o[0] = (bf16_t)v.x; o[1] = (bf16_t)v.y; o[2] = (bf16_t)v.z; o[3] = (bf16_t)v.w;
        reinterpret_cast<bf16x4*>(dst)[i] = o;
    }
}

// ---------------- GEMM 256x256, BK=32, ring-4, reg-double-buffered frags ---
// C[M,N] = (A[M,K] * B[N,K]^T + bias) * (col<qlim ? qs : 1), K=2048 fixed.
// 8 waves (2M x 4N), per-wave 128x64. LDS 128KB: 4 slots x (A 16K + B 16K).
// Within-wave overlap: while MFMAing tile t (regs), the 12 ds_reads for tile
// t+1 are interleaved between MFMA groups (no wait: not used until next tile).
// Ring-4 invariants: stage(t+3) during t overwrites slot freed at t-1;
// end-of-tile vmcnt(4) => t+2 landed before its frags are read during t+1.
template<bool OUT_BF16>
__global__ __launch_bounds__(512, 2)
void gemm256f(const bf16_t* __restrict__ A, const bf16_t* __restrict__ B,
              const float* __restrict__ b0, const float* __restrict__ b1,
              const float* __restrict__ b2, void* __restrict__ Cout,
              int M, int N, float qs, int qlim) {
    constexpr int K = 2048;
    constexpr int NK = K / 32;   // 64 (even)
    __shared__ alignas(16) unsigned char lds[131072];
    const int tid = threadIdx.x;
    const int wid = tid >> 6, l = tid & 63;
    const int cpx = gridDim.x >> 3;           // grid divisible by 8
    const int wg = (blockIdx.x & 7) * cpx + (blockIdx.x >> 3);
    const int nbm = M >> 8;
    const int bm = wg % nbm, bn = wg / nbm;
    const int wrow = (wid >> 2) * 128, wcol = (wid & 3) * 64;
    const int lr = l & 15, lg = l >> 4;

    f32x4 acc[8][4] = {};

    const bf16_t* aBase = A + (size_t)(bm * 256) * K;
    const bf16_t* bBase = B + (size_t)(bn * 256) * K;
    const int sr = l >> 2;           // 0..15: row within 16-row chunk
    const int sc = (l & 3) * 16;     // byte col within 64B row

    auto stage = [&](int t) {
        unsigned char* base = lds + (t & 3) * 32768;
#pragma unroll
        for (int c = 0; c < 2; ++c) {
            const int chunk = wid * 2 + c;
            const int r = chunk * 16 + sr;
            const int cb = sc ^ (((r >> 1) & 3) << 4);
            __builtin_amdgcn_global_load_lds(
                (const __attribute__((address_space(1))) void*)(aBase + (size_t)r * K + t * 32 + (cb >> 1)),
                (__attribute__((address_space(3))) void*)(base + chunk * 1024), 16, 0, 0);
            __builtin_amdgcn_global_load_lds(
                (const __attribute__((address_space(1))) void*)(bBase + (size_t)r * K + t * 32 + (cb >> 1)),
                (__attribute__((address_space(3))) void*)(base + 16384 + chunk * 1024), 16, 0, 0);
        }
    };

    bf16x8 fa0[8], fb0[4], fa1[8], fb1[4];

    stage(0); stage(1); stage(2);
    asm volatile("s_waitcnt vmcnt(4)" ::: "memory");   // tiles 0,1 landed; 2 in flight
    __builtin_amdgcn_s_barrier();
    {   // frags(0)
        const unsigned char* Ab = lds;
        const unsigned char* Bb = Ab + 16384;
#pragma unroll
        for (int n = 0; n < 4; ++n) {
            const int r = wcol + n * 16 + lr;
            fb0[n] = *reinterpret_cast<const bf16x8*>(Bb + r * 64 + ((lg * 16) ^ (((r >> 1) & 3) << 4)));
        }
#pragma unroll
        for (int m = 0; m < 8; ++m) {
            const int r = wrow + m * 16 + lr;
            fa0[m] = *reinterpret_cast<const bf16x8*>(Ab + r * 64 + ((lg * 16) ^ (((r >> 1) & 3) << 4)));
        }
    }

    auto step = [&](int t, bf16x8 (&ca)[8], bf16x8 (&cb)[4],
                    bf16x8 (&na)[8], bf16x8 (&nb)[4]) {
        if (t + 3 < NK) stage(t + 3);                  // slot (t+3)&3 freed at t-1
        const unsigned char* Nb = lds + ((t + 1) & 3) * 32768;  // t+1 landed+published
        const unsigned char* NbB = Nb + 16384;
        __builtin_amdgcn_s_setprio(1);
#pragma unroll
        for (int m = 0; m < 8; ++m) {
            if (m < 4) {                               // prefetch next B frag
                const int rb = wcol + m * 16 + lr;
                nb[m] = *reinterpret_cast<const bf16x8*>(NbB + rb * 64 + ((lg * 16) ^ (((rb >> 1) & 3) << 4)));
            }
            const int ra = wrow + m * 16 + lr;         // prefetch next A frag
            na[m] = *reinterpret_cast<const bf16x8*>(Nb + ra * 64 + ((lg * 16) ^ (((ra >> 1) & 3) << 4)));
#pragma unroll
            for (int n = 0; n < 4; ++n)
                acc[m][n] = __builtin_amdgcn_mfma_f32_16x16x32_bf16(ca[m], cb[n], acc[m][n], 0, 0, 0);
        }
        __builtin_amdgcn_s_setprio(0);
        if (t < NK - 1) {
            if (t + 3 < NK) asm volatile("s_waitcnt vmcnt(4)" ::: "memory");  // t+2 landed
            else            asm volatile("s_waitcnt vmcnt(0)" ::: "memory");
            __builtin_amdgcn_s_barrier();
        }
    };

#pragma unroll 1
    for (int t = 0; t < NK; t += 2) {
        step(t,     fa0, fb0, fa1, fb1);
        step(t + 1, fa1, fb1, fa0, fb0);
    }

    // epilogue: C[row=(l>>4)*4+j][col=l&15] per fragment
    const int r0 = bm * 256 + wrow + lg * 4;
    const int c0 = bn * 256 + wcol + lr;
#pragma unroll
    for (int n = 0; n < 4; ++n) {
        const int cc = c0 + n * 16;
        const float bias = (cc < 2048) ? b0[cc] : (cc < 4096 ? b1[cc - 2048] : b2[cc - 4096]);
        const float sc2 = (cc < qlim) ? qs : 1.0f;
#pragma unroll
        for (int m = 0; m < 8; ++m)
#pragma unroll
            for (int j = 0; j < 4; ++j) {
                const int rr = r0 + m * 16 + j;
                const float v = (acc[m][n][j] + bias) * sc2;
                if (OUT_BF16) ((bf16_t*)Cout)[(size_t)rr * N + cc] = (bf16_t)v;
                else          ((float*)Cout)[(size_t)rr * N + cc] = v;
            }
    }
}

// ---------------- Flash attention, 8-wave 32x32 swapped-QK^T, paired qt ----
__global__ __launch_bounds__(512, 2)
void attn_fwd3(const bf16_t* __restrict__ QKV, bf16_t* __restrict__ Og) {
    const int orig = blockIdx.x;               // 0..511
    const int id = (orig & 7) * 64 + (orig >> 3);
    const int grp = id >> 1;                   // (h, sq)
    const int pairIdx = id & 1;
    const int h = grp & 31;
    const int sq = grp >> 5;

    const int tid = threadIdx.x;
    const int w = tid >> 6;
    const int l = tid & 63;
    const int ll = l & 31;
    const int hi = l >> 5;
    const bool lo_half = (hi == 0);

    __shared__ alignas(16) unsigned char lds[65536];  // K[2][16KB] + V[2][16KB]

    const bf16_t* Qg = QKV;
    const bf16_t* Kg = QKV + 2048;
    const bf16_t* Vg = QKV + 4096;
    const size_t kvbase = (size_t)(sq * SEQLEN) * LDQ + h * 64;

    bf16x8 vr0, vr1;
    const int vk0 = l * 2;
    const int vd0 = w * 8;

    auto stageK = [&](int kt, int buf) {
#pragma unroll
        for (int c = 0; c < 2; ++c) {
            const int o = (w * 2 + c) * 1024 + l * 16;
            const int r = o >> 7;
            const int swb = (o & 127) ^ ((r & 7) << 4);
            const bf16_t* src = Kg + kvbase + (size_t)(kt * 128 + r) * LDQ + (swb >> 1);
            __builtin_amdgcn_global_load_lds(
                (const __attribute__((address_space(1))) void*)src,
                (__attribute__((address_space(3))) void*)(lds + buf * 16384 + (w * 2 + c) * 1024),
                16, 0, 0);
        }
    };
    auto loadV = [&](int kt) {
        const bf16_t* vp = Vg + kvbase + (size_t)(kt * 128 + vk0) * LDQ + vd0;
        vr0 = *reinterpret_cast<const bf16x8*>(vp);
        vr1 = *reinterpret_cast<const bf16x8*>(vp + LDQ);
    };
    auto writeV = [&](int buf) {
        u16x8 s0 = __builtin_bit_cast(u16x8, vr0);
        u16x8 s1 = __builtin_bit_cast(u16x8, vr1);
        unsigned char* vb = lds + 32768 + buf * 16384;
#pragma unroll
        for (int e = 0; e < 8; ++e) {
            const int d = vd0 + e;
            unsigned off = (unsigned)(d * 256 + vk0 * 2);
            off ^= ((unsigned)((d ^ (d >> 4)) & 15)) << 4;
            *reinterpret_cast<unsigned*>(vb + off) = (unsigned)s0[e] | ((unsigned)s1[e] << 16);
        }
    };

    const unsigned ksw = (unsigned)((l & 7) << 4);
    const unsigned kbase = (unsigned)(ll * 128 + hi * 16);

#pragma unroll 1
    for (int seg = 0; seg < 2; ++seg) {
        const int qt = pairIdx ? (seg ? 2 : 1) : (seg ? 3 : 0);

        const int q_glob = qt * 256 + w * 32 + ll;
        const bf16_t* qp = Qg + (size_t)(sq * SEQLEN + q_glob) * LDQ + h * 64 + hi * 8;
        bf16x8 qf[4];
#pragma unroll
        for (int dc = 0; dc < 4; ++dc)
            qf[dc] = *reinterpret_cast<const bf16x8*>(qp + dc * 16);

        const int nkt = 2 * qt + 2;
        const int q_wave_max = qt * 256 + w * 32 + 31;

        f32x16 oac[2] = {};
        float mrun = -3.0e38f, lsum = 0.f;

        stageK(0, 0);
        loadV(0);
        writeV(0);
        __syncthreads();

        int cur = 0;
        for (int kt = 0; kt < nkt; ++kt) {
            const bool notlast = (kt + 1 < nkt);
            if (notlast) { stageK(kt + 1, cur ^ 1); loadV(kt + 1); }

            if (kt * 128 <= q_wave_max) {
                const unsigned char* Kcur = lds + cur * 16384;
                const unsigned char* Vcur = lds + 32768 + cur * 16384;

                f32x16 st[4];
#pragma unroll
                for (int kh = 0; kh < 4; ++kh) {
                    f32x16 acc = {};
#pragma unroll
                    for (int dc = 0; dc < 4; ++dc) {
                        const unsigned off = (kbase + (unsigned)(kh * 4096 + dc * 32)) ^ ksw;
                        const bf16x8 ka = *reinterpret_cast<const bf16x8*>(Kcur + off);
                        acc = __builtin_amdgcn_mfma_f32_32x32x16_bf16(ka, qf[dc], acc, 0, 0, 0);
                    }
                    st[kh] = acc;
                }

                if (kt >= 2 * qt) {
#pragma unroll
                    for (int kh = 0; kh < 4; ++kh)
#pragma unroll
                        for (int r = 0; r < 16; ++r) {
                            const int kg = kt * 128 + kh * 32 + (r & 3) + 8 * (r >> 2) + 4 * hi;
                            if (kg > q_glob) st[kh][r] = -3.0e38f;
                        }
                }

                float tm = -3.0e38f;
#pragma unroll
                for (int kh = 0; kh < 4; ++kh)
#pragma unroll
                    for (int r = 0; r < 16; ++r) tm = fmaxf(tm, st[kh][r]);
                tm = fmaxf(tm, __shfl_xor(tm, 32));

                if (!__all(tm <= mrun + 8.0f)) {
                    const float mnew = fmaxf(mrun, tm);
                    const float rsc = EXP2F(mrun - mnew);
                    mrun = mnew;
                    lsum *= rsc;
#pragma unroll
                    for (int dh = 0; dh < 2; ++dh)
#pragma unroll
                        for (int r = 0; r < 16; ++r) oac[dh][r] *= rsc;
                }

                float ps = 0.f;
#pragma unroll
                for (int kh = 0; kh < 4; ++kh)
#pragma unroll
                    for (int r = 0; r < 16; ++r) {
                        const float p = EXP2F(st[kh][r] - mrun);
                        st[kh][r] = p;
                        ps += p;
                    }
                ps += __shfl_xor(ps, 32);
                lsum += ps;

                bf16x8 pf[8];
#pragma unroll
                for (int kh = 0; kh < 4; ++kh)
#pragma unroll
                    for (int hc = 0; hc < 2; ++hc) {
                        const int b0i = hc * 8;
                        unsigned a  = cvtpk_bf16(st[kh][b0i + 0], st[kh][b0i + 1]);
                        unsigned b  = cvtpk_bf16(st[kh][b0i + 4], st[kh][b0i + 5]);
                        unsigned a2 = cvtpk_bf16(st[kh][b0i + 2], st[kh][b0i + 3]);
                        unsigned b2 = cvtpk_bf16(st[kh][b0i + 6], st[kh][b0i + 7]);
                        plswap(a, b, lo_half);
                        plswap(a2, b2, lo_half);
                        u32x4 words = { a, a2, b, b2 };
                        pf[kh * 2 + hc] = __builtin_bit_cast(bf16x8, words);
                    }

#pragma unroll
                for (int dh = 0; dh < 2; ++dh) {
                    const int d = dh * 32 + ll;
                    const unsigned vsw = ((unsigned)((d ^ (d >> 4)) & 15)) << 4;
                    const unsigned vbb = (unsigned)(d * 256 + hi * 16);
#pragma unroll
                    for (int kc = 0; kc < 8; ++kc) {
                        const unsigned off = (vbb + (unsigned)(kc * 32)) ^ vsw;
                        const bf16x8 vfr = *reinterpret_cast<const bf16x8*>(Vcur + off);
                        oac[dh] = __builtin_amdgcn_mfma_f32_32x32x16_bf16(vfr, pf[kc], oac[dh], 0, 0, 0);
                    }
                }
            }

            if (notlast) writeV(cur ^ 1);
            __syncthreads();
            cur ^= 1;
        }

        const float inv = 1.0f / lsum;
        bf16_t* op = Og + (size_t)(sq * SEQLEN + q_glob) * E_DIM + h * 64;
#pragma unroll
        for (int dh = 0; dh < 2; ++dh)
#pragma unroll
            for (int rq = 0; rq < 4; ++rq) {
                const int d0 = dh * 32 + 8 * rq + 4 * hi;
                bf16x4 ov;
#pragma unroll
                for (int j = 0; j < 4; ++j)
                    ov[j] = (bf16_t)(oac[dh][rq * 4 + j] * inv);
                *reinterpret_cast<bf16x4*>(op + d0) = ov;
            }
    }
}

// ---------------------------------------------------------------------------
extern "C" void kernel_launch(void* const* d_in, const int* in_sizes, int n_in,
                              void* d_out, int out_size, void* d_ws, size_t ws_size,
                              hipStream_t stream) {
    const float* hid = (const float*)d_in[0];
    const float* Wq  = (const float*)d_in[1];
    const float* bq  = (const float*)d_in[2];
    const float* Wk  = (const float*)d_in[3];
    const float* bk  = (const float*)d_in[4];
    const float* Wv  = (const float*)d_in[5];
    const float* bv  = (const float*)d_in[6];
    const float* Wo  = (const float*)d_in[7];
    const float* bo  = (const float*)d_in[8];
    float* out = (float*)d_out;

    const size_t TE = (size_t)T_TOK * E_DIM;
    const size_t EE = (size_t)E_DIM * E_DIM;

    bf16_t* ws   = (bf16_t*)d_ws;
    bf16_t* hidB = ws;                 // later reused as attention output
    bf16_t* qkvB = ws + TE;            // [8192][6144]
    bf16_t* Wcat = qkvB + 3 * TE;      // [6144][2048] = Wq|Wk|Wv rows
    bf16_t* WoB  = Wcat + 3 * EE;

    cvt_all<<<4096, 256, 0, stream>>>(hid, Wq, Wk, Wv, Wo, hidB, Wcat, WoB);

    // Q pre-scaled by D^-0.5 * log2(e): attention runs in exp2 domain.
    const float QSCALE = 0.125f * 1.4426950408889634f;

    gemm256f<true><<<dim3((T_TOK / 256) * (LDQ / 256)), 512, 0, stream>>>(
        hidB, Wcat, bq, bk, bv, qkvB, T_TOK, LDQ, QSCALE, 2048);

    attn_fwd3<<<dim3(512), 512, 0, stream>>>(qkvB, hidB);

    gemm256f<false><<<dim3((T_TOK / 256) * (E_DIM / 256)), 512, 0, stream>>>(
        hidB, WoB, bo, bo, bo, out, T_TOK, E_DIM, 1.0f, 0);
}

// Round 7
// 394.615 us; speedup vs baseline: 1.5196x; 1.0083x over previous
//
#include <hip/hip_runtime.h>
#include <hip/hip_bf16.h>

typedef __bf16 bf16_t;
typedef __bf16 bf16x8 __attribute__((ext_vector_type(8)));
typedef __bf16 bf16x4 __attribute__((ext_vector_type(4)));
typedef float f32x4 __attribute__((ext_vector_type(4)));
typedef float f32x16 __attribute__((ext_vector_type(16)));
typedef unsigned short u16x8 __attribute__((ext_vector_type(8)));
typedef unsigned int u32x4 __attribute__((ext_vector_type(4)));

#define T_TOK 8192
#define E_DIM 2048
#define NHEAD 32
#define SEQLEN 1024
#define NSEQ 8
#define LDQ 6144

#if __has_builtin(__builtin_amdgcn_exp2f)
#define EXP2F(x) __builtin_amdgcn_exp2f(x)
#else
#define EXP2F(x) exp2f(x)
#endif

static __device__ inline unsigned cvtpk_bf16(float lo, float hi) {
    unsigned r;
    asm("v_cvt_pk_bf16_f32 %0, %1, %2" : "=v"(r) : "v"(lo), "v"(hi));
    return r;
}

static __device__ inline void plswap(unsigned &x, unsigned &y, bool lo_half) {
#if __has_builtin(__builtin_amdgcn_permlane32_swap)
    auto r = __builtin_amdgcn_permlane32_swap(x, y, false, false);
    x = r[0]; y = r[1];
#else
    unsigned xs = __shfl_xor(x, 32), ys = __shfl_xor(y, 32);
    unsigned nx = lo_half ? x : ys;
    unsigned ny = lo_half ? xs : y;
    x = nx; y = ny;
#endif
}

// ---------------- fused fp32 -> bf16 conversion (5 regions, 1 launch) ------
__global__ void cvt_all(const float* __restrict__ hid, const float* __restrict__ Wq,
                        const float* __restrict__ Wk, const float* __restrict__ Wv,
                        const float* __restrict__ Wo, bf16_t* __restrict__ hidB,
                        bf16_t* __restrict__ Wcat, bf16_t* __restrict__ WoB) {
    const int TE4 = (T_TOK * E_DIM) / 4;
    const int EE4 = (E_DIM * E_DIM) / 4;
    const float* src;
    bf16_t* dst;
    int n4, base, nb;
    const int bid = blockIdx.x;
    if (bid < 2048)      { src = hid; dst = hidB;              n4 = TE4; base = 0;    nb = 2048; }
    else if (bid < 2560) { src = Wq;  dst = Wcat;              n4 = EE4; base = 2048; nb = 512; }
    else if (bid < 3072) { src = Wk;  dst = Wcat + 4 * EE4;    n4 = EE4; base = 2560; nb = 512; }
    else if (bid < 3584) { src = Wv;  dst = Wcat + 8 * EE4;    n4 = EE4; base = 3072; nb = 512; }
    else                 { src = Wo;  dst = WoB;               n4 = EE4; base = 3584; nb = 512; }
    const int stride = nb * 256;
    for (int i = (bid - base) * 256 + threadIdx.x; i < n4; i += stride) {
        const float4 v = reinterpret_cast<const float4*>(src)[i];
        bf16x4 o;
        o[0] = (bf16_t)v.x; o[1] = (bf16_t)v.y; o[2] = (bf16_t)v.z; o[3] = (bf16_t)v.w;
        reinterpret_cast<bf16x4*>(dst)[i] = o;
    }
}

// ---------------- GEMM 256x256, BK=64, m201-style 8-phase schedule --------
// C[M,N] = (A[M,K] * B[N,K]^T + bias) * (col<qlim ? qs : 1), K=2048 fixed.
// 8 waves (2M x 4N), per-wave 128x64 = 8m x 4n frags, K-tile 64 = 2 ksubs.
// LDS 128KB: [2 dbuf][A0|A1|B0|B1][16KB half-slot] (half = 128 rows x 64 col).
// Per tile (4 phases, quadrant (mh,nh)): {ds_reads; stage 1 half; bar;
// lgkm(0); setprio1; 16 MFMA; setprio0; bar}. Stage ring: p0:A1(t+1),
// p1:B1(t+1), p2:A0(t+2), p3:B0(t+2); vmcnt(4) ONCE per tile at tile end.
// Swizzle: 128B rows, cb ^= (row&7)<<4 (conflict-free; 2-way residual).
template<bool OUT_BF16>
__global__ __launch_bounds__(512, 2)
void gemm8p(const bf16_t* __restrict__ A, const bf16_t* __restrict__ B,
            const float* __restrict__ b0, const float* __restrict__ b1,
            const float* __restrict__ b2, void* __restrict__ Cout,
            int M, int N, float qs, int qlim) {
    constexpr int K = 2048;
    constexpr int NK = K / 64;   // 32
    __shared__ alignas(16) unsigned char lds[131072];
    const int tid = threadIdx.x;
    const int wid = tid >> 6, l = tid & 63;
    const int cpx = gridDim.x >> 3;           // grid divisible by 8
    const int wg = (blockIdx.x & 7) * cpx + (blockIdx.x >> 3);
    const int nbm = M >> 8;
    const int bm = wg % nbm, bn = wg / nbm;
    const int wrow = (wid >> 2) * 128, wcol = (wid & 3) * 64;
    const int lr = l & 15, lg = l >> 4;

    f32x4 acc[8][4] = {};

    const bf16_t* aB = A + (size_t)(bm * 256) * K;
    const bf16_t* bB = B + (size_t)(bn * 256) * K;

    // stage precompute: chunk = wid*2+c, o = chunk*1024 + l*16 within 16KB half
    int rl[2], cbs[2];
#pragma unroll
    for (int c = 0; c < 2; ++c) {
        const int o = (wid * 2 + c) * 1024 + l * 16;
        rl[c] = o >> 7;                        // local row 0..127
        cbs[c] = (o & 127) ^ ((rl[c] & 7) << 4);  // pre-swizzled src col byte
    }
    auto stageHalf = [&](int t, int op, int h) {
        const bf16_t* s0 = op ? bB : aB;
        unsigned char* dst = lds + (t & 1) * 65536 + (op * 2 + h) * 16384;
#pragma unroll
        for (int c = 0; c < 2; ++c) {
            const bf16_t* src = s0 + (size_t)(h * 128 + rl[c]) * K + t * 64 + (cbs[c] >> 1);
            __builtin_amdgcn_global_load_lds(
                (const __attribute__((address_space(1))) void*)src,
                (__attribute__((address_space(3))) void*)(dst + (wid * 2 + c) * 1024), 16, 0, 0);
        }
    };

    const unsigned aSlot = (unsigned)((wrow >> 7) * 16384);
    const unsigned bSlot = (unsigned)((2 + (wcol >> 7)) * 16384);
    const unsigned swz = (unsigned)((lr & 7) << 4);
    const int bRow0 = (wcol & 64);

    bf16x8 af[4][2], bf[4][2];
    auto loadA = [&](int t, int mh) {
        const unsigned char* base = lds + (t & 1) * 65536 + aSlot;
#pragma unroll
        for (int mi = 0; mi < 4; ++mi)
#pragma unroll
            for (int ks = 0; ks < 2; ++ks)
                af[mi][ks] = *reinterpret_cast<const bf16x8*>(
                    base + ((mh * 4 + mi) * 16 + lr) * 128 + (((unsigned)(ks * 64 + lg * 16)) ^ swz));
    };
    auto loadB2 = [&](int t, int nh) {   // 4 reads: n = nh*2, nh*2+1
        const unsigned char* base = lds + (t & 1) * 65536 + bSlot;
#pragma unroll
        for (int ni = 0; ni < 2; ++ni)
#pragma unroll
            for (int ks = 0; ks < 2; ++ks)
                bf[nh * 2 + ni][ks] = *reinterpret_cast<const bf16x8*>(
                    base + (bRow0 + (nh * 2 + ni) * 16 + lr) * 128 + (((unsigned)(ks * 64 + lg * 16)) ^ swz));
    };
    auto mfmaQuad = [&](int mh, int nh) {
        __builtin_amdgcn_s_setprio(1);
#pragma unroll
        for (int mi = 0; mi < 4; ++mi)
#pragma unroll
            for (int ni = 0; ni < 2; ++ni)
#pragma unroll
                for (int ks = 0; ks < 2; ++ks)
                    acc[mh * 4 + mi][nh * 2 + ni] = __builtin_amdgcn_mfma_f32_16x16x32_bf16(
                        af[mi][ks], bf[nh * 2 + ni][ks], acc[mh * 4 + mi][nh * 2 + ni], 0, 0, 0);
        __builtin_amdgcn_s_setprio(0);
    };
#define LGKM0 do { asm volatile("s_waitcnt lgkmcnt(0)" ::: "memory"); __builtin_amdgcn_sched_barrier(0); } while (0)
#define BAR __builtin_amdgcn_s_barrier()

    // prologue: tile0 complete + first halves of tile1; vmcnt(4) => tile0 landed
    stageHalf(0, 0, 0); stageHalf(0, 1, 0); stageHalf(0, 0, 1); stageHalf(0, 1, 1);
    stageHalf(1, 0, 0); stageHalf(1, 1, 0);
    asm volatile("s_waitcnt vmcnt(4)" ::: "memory");
    BAR;

#pragma unroll 1
    for (int t = 0; t < NK; ++t) {
        // phase 0: 12 reads (A mh0 + B nh0), stage A1(t+1)
        loadA(t, 0); loadB2(t, 0);
        if (t + 1 < NK) stageHalf(t + 1, 0, 1);
        BAR; LGKM0; mfmaQuad(0, 0); BAR;
        // phase 1: 4 reads (B nh1), stage B1(t+1)
        loadB2(t, 1);
        if (t + 1 < NK) stageHalf(t + 1, 1, 1);
        BAR; LGKM0; mfmaQuad(0, 1); BAR;
        // phase 2: 8 reads (A mh1), stage A0(t+2)
        loadA(t, 1);
        if (t + 2 < NK) stageHalf(t + 2, 0, 0);
        BAR; LGKM0; mfmaQuad(1, 0); BAR;
        // phase 3: 0 reads, stage B0(t+2)
        if (t + 2 < NK) stageHalf(t + 2, 1, 0);
        BAR; LGKM0; mfmaQuad(1, 1);
        if (t == NK - 1) break;
        if (t + 2 < NK) asm volatile("s_waitcnt vmcnt(4)" ::: "memory");
        else            asm volatile("s_waitcnt vmcnt(0)" ::: "memory");
        BAR;
    }
#undef LGKM0
#undef BAR

    // epilogue: C[row=(l>>4)*4+j][col=l&15] per fragment
    const int r0 = bm * 256 + wrow + lg * 4;
    const int c0 = bn * 256 + wcol + lr;
#pragma unroll
    for (int n = 0; n < 4; ++n) {
        const int cc = c0 + n * 16;
        const float bias = (cc < 2048) ? b0[cc] : (cc < 4096 ? b1[cc - 2048] : b2[cc - 4096]);
        const float sc2 = (cc < qlim) ? qs : 1.0f;
#pragma unroll
        for (int m = 0; m < 8; ++m)
#pragma unroll
            for (int j = 0; j < 4; ++j) {
                const int rr = r0 + m * 16 + j;
                const float v = (acc[m][n][j] + bias) * sc2;
                if (OUT_BF16) ((bf16_t*)Cout)[(size_t)rr * N + cc] = (bf16_t)v;
                else          ((float*)Cout)[(size_t)rr * N + cc] = v;
            }
    }
}

// ---------------- Flash attention, 8-wave 32x32 swapped-QK^T, paired qt ----
__global__ __launch_bounds__(512, 2)
void attn_fwd3(const bf16_t* __restrict__ QKV, bf16_t* __restrict__ Og) {
    const int orig = blockIdx.x;               // 0..511
    const int id = (orig & 7) * 64 + (orig >> 3);
    const int grp = id >> 1;                   // (h, sq)
    const int pairIdx = id & 1;
    const int h = grp & 31;
    const int sq = grp >> 5;

    const int tid = threadIdx.x;
    const int w = tid >> 6;
    const int l = tid & 63;
    const int ll = l & 31;
    const int hi = l >> 5;
    const bool lo_half = (hi == 0);

    __shared__ alignas(16) unsigned char lds[65536];  // K[2][16KB] + V[2][16KB]

    const bf16_t* Qg = QKV;
    const bf16_t* Kg = QKV + 2048;
    const bf16_t* Vg = QKV + 4096;
    const size_t kvbase = (size_t)(sq * SEQLEN) * LDQ + h * 64;

    bf16x8 vr0, vr1;
    const int vk0 = l * 2;
    const int vd0 = w * 8;

    auto stageK = [&](int kt, int buf) {
#pragma unroll
        for (int c = 0; c < 2; ++c) {
            const int o = (w * 2 + c) * 1024 + l * 16;
            const int r = o >> 7;
            const int swb = (o & 127) ^ ((r & 7) << 4);
            const bf16_t* src = Kg + kvbase + (size_t)(kt * 128 + r) * LDQ + (swb >> 1);
            __builtin_amdgcn_global_load_lds(
                (const __attribute__((address_space(1))) void*)src,
                (__attribute__((address_space(3))) void*)(lds + buf * 16384 + (w * 2 + c) * 1024),
                16, 0, 0);
        }
    };
    auto loadV = [&](int kt) {
        const bf16_t* vp = Vg + kvbase + (size_t)(kt * 128 + vk0) * LDQ + vd0;
        vr0 = *reinterpret_cast<const bf16x8*>(vp);
        vr1 = *reinterpret_cast<const bf16x8*>(vp + LDQ);
    };
    auto writeV = [&](int buf) {
        u16x8 s0 = __builtin_bit_cast(u16x8, vr0);
        u16x8 s1 = __builtin_bit_cast(u16x8, vr1);
        unsigned char* vb = lds + 32768 + buf * 16384;
#pragma unroll
        for (int e = 0; e < 8; ++e) {
            const int d = vd0 + e;
            unsigned off = (unsigned)(d * 256 + vk0 * 2);
            off ^= ((unsigned)((d ^ (d >> 4)) & 15)) << 4;
            *reinterpret_cast<unsigned*>(vb + off) = (unsigned)s0[e] | ((unsigned)s1[e] << 16);
        }
    };

    const unsigned ksw = (unsigned)((l & 7) << 4);
    const unsigned kbase = (unsigned)(ll * 128 + hi * 16);

#pragma unroll 1
    for (int seg = 0; seg < 2; ++seg) {
        const int qt = pairIdx ? (seg ? 2 : 1) : (seg ? 3 : 0);

        const int q_glob = qt * 256 + w * 32 + ll;
        const bf16_t* qp = Qg + (size_t)(sq * SEQLEN + q_glob) * LDQ + h * 64 + hi * 8;
        bf16x8 qf[4];
#pragma unroll
        for (int dc = 0; dc < 4; ++dc)
            qf[dc] = *reinterpret_cast<const bf16x8*>(qp + dc * 16);

        const int nkt = 2 * qt + 2;
        const int q_wave_max = qt * 256 + w * 32 + 31;

        f32x16 oac[2] = {};
        float mrun = -3.0e38f, lsum = 0.f;

        stageK(0, 0);
        loadV(0);
        writeV(0);
        __syncthreads();

        int cur = 0;
        for (int kt = 0; kt < nkt; ++kt) {
            const bool notlast = (kt + 1 < nkt);
            if (notlast) { stageK(kt + 1, cur ^ 1); loadV(kt + 1); }

            if (kt * 128 <= q_wave_max) {
                const unsigned char* Kcur = lds + cur * 16384;
                const unsigned char* Vcur = lds + 32768 + cur * 16384;

                f32x16 st[4];
#pragma unroll
                for (int kh = 0; kh < 4; ++kh) {
                    f32x16 acc = {};
#pragma unroll
                    for (int dc = 0; dc < 4; ++dc) {
                        const unsigned off = (kbase + (unsigned)(kh * 4096 + dc * 32)) ^ ksw;
                        const bf16x8 ka = *reinterpret_cast<const bf16x8*>(Kcur + off);
                        acc = __builtin_amdgcn_mfma_f32_32x32x16_bf16(ka, qf[dc], acc, 0, 0, 0);
                    }
                    st[kh] = acc;
                }

                if (kt >= 2 * qt) {
#pragma unroll
                    for (int kh = 0; kh < 4; ++kh)
#pragma unroll
                        for (int r = 0; r < 16; ++r) {
                            const int kg = kt * 128 + kh * 32 + (r & 3) + 8 * (r >> 2) + 4 * hi;
                            if (kg > q_glob) st[kh][r] = -3.0e38f;
                        }
                }

                float tm = -3.0e38f;
#pragma unroll
                for (int kh = 0; kh < 4; ++kh)
#pragma unroll
                    for (int r = 0; r < 16; ++r) tm = fmaxf(tm, st[kh][r]);
                tm = fmaxf(tm, __shfl_xor(tm, 32));

                if (!__all(tm <= mrun + 8.0f)) {
                    const float mnew = fmaxf(mrun, tm);
                    const float rsc = EXP2F(mrun - mnew);
                    mrun = mnew;
                    lsum *= rsc;
#pragma unroll
                    for (int dh = 0; dh < 2; ++dh)
#pragma unroll
                        for (int r = 0; r < 16; ++r) oac[dh][r] *= rsc;
                }

                float ps = 0.f;
#pragma unroll
                for (int kh = 0; kh < 4; ++kh)
#pragma unroll
                    for (int r = 0; r < 16; ++r) {
                        const float p = EXP2F(st[kh][r] - mrun);
                        st[kh][r] = p;
                        ps += p;
                    }
                ps += __shfl_xor(ps, 32);
                lsum += ps;

                bf16x8 pf[8];
#pragma unroll
                for (int kh = 0; kh < 4; ++kh)
#pragma unroll
                    for (int hc = 0; hc < 2; ++hc) {
                        const int b0i = hc * 8;
                        unsigned a  = cvtpk_bf16(st[kh][b0i + 0], st[kh][b0i + 1]);
                        unsigned b  = cvtpk_bf16(st[kh][b0i + 4], st[kh][b0i + 5]);
                        unsigned a2 = cvtpk_bf16(st[kh][b0i + 2], st[kh][b0i + 3]);
                        unsigned b2 = cvtpk_bf16(st[kh][b0i + 6], st[kh][b0i + 7]);
                        plswap(a, b, lo_half);
                        plswap(a2, b2, lo_half);
                        u32x4 words = { a, a2, b, b2 };
                        pf[kh * 2 + hc] = __builtin_bit_cast(bf16x8, words);
                    }

#pragma unroll
                for (int dh = 0; dh < 2; ++dh) {
                    const int d = dh * 32 + ll;
                    const unsigned vsw = ((unsigned)((d ^ (d >> 4)) & 15)) << 4;
                    const unsigned vbb = (unsigned)(d * 256 + hi * 16);
#pragma unroll
                    for (int kc = 0; kc < 8; ++kc) {
                        const unsigned off = (vbb + (unsigned)(kc * 32)) ^ vsw;
                        const bf16x8 vfr = *reinterpret_cast<const bf16x8*>(Vcur + off);
                        oac[dh] = __builtin_amdgcn_mfma_f32_32x32x16_bf16(vfr, pf[kc], oac[dh], 0, 0, 0);
                    }
                }
            }

            if (notlast) writeV(cur ^ 1);
            __syncthreads();
            cur ^= 1;
        }

        const float inv = 1.0f / lsum;
        bf16_t* op = Og + (size_t)(sq * SEQLEN + q_glob) * E_DIM + h * 64;
#pragma unroll
        for (int dh = 0; dh < 2; ++dh)
#pragma unroll
            for (int rq = 0; rq < 4; ++rq) {
                const int d0 = dh * 32 + 8 * rq + 4 * hi;
                bf16x4 ov;
#pragma unroll
                for (int j = 0; j < 4; ++j)
                    ov[j] = (bf16_t)(oac[dh][rq * 4 + j] * inv);
                *reinterpret_cast<bf16x4*>(op + d0) = ov;
            }
    }
}

// ---------------------------------------------------------------------------
extern "C" void kernel_launch(void* const* d_in, const int* in_sizes, int n_in,
                              void* d_out, int out_size, void* d_ws, size_t ws_size,
                              hipStream_t stream) {
    const float* hid = (const float*)d_in[0];
    const float* Wq  = (const float*)d_in[1];
    const float* bq  = (const float*)d_in[2];
    const float* Wk  = (const float*)d_in[3];
    const float* bk  = (const float*)d_in[4];
    const float* Wv  = (const float*)d_in[5];
    const float* bv  = (const float*)d_in[6];
    const float* Wo  = (const float*)d_in[7];
    const float* bo  = (const float*)d_in[8];
    float* out = (float*)d_out;

    const size_t TE = (size_t)T_TOK * E_DIM;
    const size_t EE = (size_t)E_DIM * E_DIM;

    bf16_t* ws   = (bf16_t*)d_ws;
    bf16_t* hidB = ws;                 // later reused as attention output
    bf16_t* qkvB = ws + TE;            // [8192][6144]
    bf16_t* Wcat = qkvB + 3 * TE;      // [6144][2048] = Wq|Wk|Wv rows
    bf16_t* WoB  = Wcat + 3 * EE;

    cvt_all<<<4096, 256, 0, stream>>>(hid, Wq, Wk, Wv, Wo, hidB, Wcat, WoB);

    // Q pre-scaled by D^-0.5 * log2(e): attention runs in exp2 domain.
    const float QSCALE = 0.125f * 1.4426950408889634f;

    gemm8p<true><<<dim3((T_TOK / 256) * (LDQ / 256)), 512, 0, stream>>>(
        hidB, Wcat, bq, bk, bv, qkvB, T_TOK, LDQ, QSCALE, 2048);

    attn_fwd3<<<dim3(512), 512, 0, stream>>>(qkvB, hidB);

    gemm8p<false><<<dim3((T_TOK / 256) * (E_DIM / 256)), 512, 0, stream>>>(
        hidB, WoB, bo, bo, bo, out, T_TOK, E_DIM, 1.0f, 0);
}

// Round 8
// 385.625 us; speedup vs baseline: 1.5551x; 1.0233x over previous
//
#include <hip/hip_runtime.h>
#include <hip/hip_bf16.h>

typedef __bf16 bf16_t;
typedef __bf16 bf16x8 __attribute__((ext_vector_type(8)));
typedef __bf16 bf16x4 __attribute__((ext_vector_type(4)));
typedef float f32x4 __attribute__((ext_vector_type(4)));
typedef float f32x16 __attribute__((ext_vector_type(16)));
typedef unsigned short u16x8 __attribute__((ext_vector_type(8)));
typedef unsigned int u32x4 __attribute__((ext_vector_type(4)));

#define T_TOK 8192
#define E_DIM 2048
#define NHEAD 32
#define SEQLEN 1024
#define NSEQ 8
#define LDQ 6144

#if __has_builtin(__builtin_amdgcn_exp2f)
#define EXP2F(x) __builtin_amdgcn_exp2f(x)
#else
#define EXP2F(x) exp2f(x)
#endif

static __device__ inline unsigned cvtpk_bf16(float lo, float hi) {
    unsigned r;
    asm("v_cvt_pk_bf16_f32 %0, %1, %2" : "=v"(r) : "v"(lo), "v"(hi));
    return r;
}

static __device__ inline void plswap(unsigned &x, unsigned &y, bool lo_half) {
#if __has_builtin(__builtin_amdgcn_permlane32_swap)
    auto r = __builtin_amdgcn_permlane32_swap(x, y, false, false);
    x = r[0]; y = r[1];
#else
    unsigned xs = __shfl_xor(x, 32), ys = __shfl_xor(y, 32);
    unsigned nx = lo_half ? x : ys;
    unsigned ny = lo_half ? xs : y;
    x = nx; y = ny;
#endif
}

// ---------------- fused fp32 -> bf16 conversion (5 regions, 1 launch) ------
__global__ void cvt_all(const float* __restrict__ hid, const float* __restrict__ Wq,
                        const float* __restrict__ Wk, const float* __restrict__ Wv,
                        const float* __restrict__ Wo, bf16_t* __restrict__ hidB,
                        bf16_t* __restrict__ Wcat, bf16_t* __restrict__ WoB) {
    const int TE4 = (T_TOK * E_DIM) / 4;
    const int EE4 = (E_DIM * E_DIM) / 4;
    const float* src;
    bf16_t* dst;
    int n4, base, nb;
    const int bid = blockIdx.x;
    if (bid < 2048)      { src = hid; dst = hidB;              n4 = TE4; base = 0;    nb = 2048; }
    else if (bid < 2560) { src = Wq;  dst = Wcat;              n4 = EE4; base = 2048; nb = 512; }
    else if (bid < 3072) { src = Wk;  dst = Wcat + 4 * EE4;    n4 = EE4; base = 2560; nb = 512; }
    else if (bid < 3584) { src = Wv;  dst = Wcat + 8 * EE4;    n4 = EE4; base = 3072; nb = 512; }
    else                 { src = Wo;  dst = WoB;               n4 = EE4; base = 3584; nb = 512; }
    const int stride = nb * 256;
    for (int i = (bid - base) * 256 + threadIdx.x; i < n4; i += stride) {
        const float4 v = reinterpret_cast<const float4*>(src)[i];
        bf16x4 o;
        o[0] = (bf16_t)v.x; o[1] = (bf16_t)v.y; o[2] = (bf16_t)v.z; o[3] = (bf16_t)v.w;
        reinterpret_cast<bf16x4*>(dst)[i] = o;
    }
}

// ---------------- GEMM 256x256, BK=32, ring-4, reg-double-buffered frags ---
// C[M,N] = (A[M,K] * B[N,K]^T + bias) * (col<qlim ? qs : 1), K=2048 fixed.
// 8 waves (2M x 4N), per-wave 128x64. LDS 128KB: 4 slots x (A 16K + B 16K).
// Best-measured structure (R6: 908 TF). This round adds an 8x4 supertile
// (bm,bn) map inside each XCD chunk: 32-block supertile working set =
// 8 A-panels + 4 B-panels = 12 MB (vs 35 MB for the flat map) -> less L2
// thrash, lower staging latency. Mapping is bijective for grids 768 and 256.
template<bool OUT_BF16>
__global__ __launch_bounds__(512, 2)
void gemm256f(const bf16_t* __restrict__ A, const bf16_t* __restrict__ B,
              const float* __restrict__ b0, const float* __restrict__ b1,
              const float* __restrict__ b2, void* __restrict__ Cout,
              int M, int N, float qs, int qlim) {
    constexpr int K = 2048;
    constexpr int NK = K / 32;   // 64 (even)
    __shared__ alignas(16) unsigned char lds[131072];
    const int tid = threadIdx.x;
    const int wid = tid >> 6, l = tid & 63;
    // XCD chunking (grid divisible by 8), then 8bm x 4bn supertiles of 32 ids.
    const int cpx = gridDim.x >> 3;
    const int id = (blockIdx.x & 7) * cpx + (blockIdx.x >> 3);
    const int sb = id >> 5, si = id & 31;
    const int smw = (M >> 8) >> 3;            // supertiles per bm-band (nbm/8)
    const int bm = (sb % smw) * 8 + (si & 7);
    const int bn = (sb / smw) * 4 + (si >> 3);
    const int wrow = (wid >> 2) * 128, wcol = (wid & 3) * 64;
    const int lr = l & 15, lg = l >> 4;

    f32x4 acc[8][4] = {};

    const bf16_t* aBase = A + (size_t)(bm * 256) * K;
    const bf16_t* bBase = B + (size_t)(bn * 256) * K;
    const int sr = l >> 2;           // 0..15: row within 16-row chunk
    const int sc = (l & 3) * 16;     // byte col within 64B row

    auto stage = [&](int t) {
        unsigned char* base = lds + (t & 3) * 32768;
#pragma unroll
        for (int c = 0; c < 2; ++c) {
            const int chunk = wid * 2 + c;
            const int r = chunk * 16 + sr;
            const int cb = sc ^ (((r >> 1) & 3) << 4);
            __builtin_amdgcn_global_load_lds(
                (const __attribute__((address_space(1))) void*)(aBase + (size_t)r * K + t * 32 + (cb >> 1)),
                (__attribute__((address_space(3))) void*)(base + chunk * 1024), 16, 0, 0);
            __builtin_amdgcn_global_load_lds(
                (const __attribute__((address_space(1))) void*)(bBase + (size_t)r * K + t * 32 + (cb >> 1)),
                (__attribute__((address_space(3))) void*)(base + 16384 + chunk * 1024), 16, 0, 0);
        }
    };

    bf16x8 fa0[8], fb0[4], fa1[8], fb1[4];

    stage(0); stage(1); stage(2);
    asm volatile("s_waitcnt vmcnt(4)" ::: "memory");   // tiles 0,1 landed; 2 in flight
    __builtin_amdgcn_s_barrier();
    {   // frags(0)
        const unsigned char* Ab = lds;
        const unsigned char* Bb = Ab + 16384;
#pragma unroll
        for (int n = 0; n < 4; ++n) {
            const int r = wcol + n * 16 + lr;
            fb0[n] = *reinterpret_cast<const bf16x8*>(Bb + r * 64 + ((lg * 16) ^ (((r >> 1) & 3) << 4)));
        }
#pragma unroll
        for (int m = 0; m < 8; ++m) {
            const int r = wrow + m * 16 + lr;
            fa0[m] = *reinterpret_cast<const bf16x8*>(Ab + r * 64 + ((lg * 16) ^ (((r >> 1) & 3) << 4)));
        }
    }

    auto step = [&](int t, bf16x8 (&ca)[8], bf16x8 (&cb)[4],
                    bf16x8 (&na)[8], bf16x8 (&nb)[4]) {
        if (t + 3 < NK) stage(t + 3);                  // slot (t+3)&3 freed at t-1
        const unsigned char* Nb = lds + ((t + 1) & 3) * 32768;  // t+1 landed+published
        const unsigned char* NbB = Nb + 16384;
        __builtin_amdgcn_s_setprio(1);
#pragma unroll
        for (int m = 0; m < 8; ++m) {
            if (m < 4) {                               // prefetch next B frag
                const int rb = wcol + m * 16 + lr;
                nb[m] = *reinterpret_cast<const bf16x8*>(NbB + rb * 64 + ((lg * 16) ^ (((rb >> 1) & 3) << 4)));
            }
            const int ra = wrow + m * 16 + lr;         // prefetch next A frag
            na[m] = *reinterpret_cast<const bf16x8*>(Nb + ra * 64 + ((lg * 16) ^ (((ra >> 1) & 3) << 4)));
#pragma unroll
            for (int n = 0; n < 4; ++n)
                acc[m][n] = __builtin_amdgcn_mfma_f32_16x16x32_bf16(ca[m], cb[n], acc[m][n], 0, 0, 0);
        }
        __builtin_amdgcn_s_setprio(0);
        if (t < NK - 1) {
            if (t + 3 < NK) asm volatile("s_waitcnt vmcnt(4)" ::: "memory");  // t+2 landed
            else            asm volatile("s_waitcnt vmcnt(0)" ::: "memory");
            __builtin_amdgcn_s_barrier();
        }
    };

#pragma unroll 1
    for (int t = 0; t < NK; t += 2) {
        step(t,     fa0, fb0, fa1, fb1);
        step(t + 1, fa1, fb1, fa0, fb0);
    }

    // epilogue: C[row=(l>>4)*4+j][col=l&15] per fragment
    const int r0 = bm * 256 + wrow + lg * 4;
    const int c0 = bn * 256 + wcol + lr;
#pragma unroll
    for (int n = 0; n < 4; ++n) {
        const int cc = c0 + n * 16;
        const float bias = (cc < 2048) ? b0[cc] : (cc < 4096 ? b1[cc - 2048] : b2[cc - 4096]);
        const float sc2 = (cc < qlim) ? qs : 1.0f;
#pragma unroll
        for (int m = 0; m < 8; ++m)
#pragma unroll
            for (int j = 0; j < 4; ++j) {
                const int rr = r0 + m * 16 + j;
                const float v = (acc[m][n][j] + bias) * sc2;
                if (OUT_BF16) ((bf16_t*)Cout)[(size_t)rr * N + cc] = (bf16_t)v;
                else          ((float*)Cout)[(size_t)rr * N + cc] = v;
            }
    }
}

// ---------------- Flash attention, 8-wave 32x32 swapped-QK^T, paired qt ----
__global__ __launch_bounds__(512, 2)
void attn_fwd3(const bf16_t* __restrict__ QKV, bf16_t* __restrict__ Og) {
    const int orig = blockIdx.x;               // 0..511
    const int id = (orig & 7) * 64 + (orig >> 3);
    const int grp = id >> 1;                   // (h, sq)
    const int pairIdx = id & 1;
    const int h = grp & 31;
    const int sq = grp >> 5;

    const int tid = threadIdx.x;
    const int w = tid >> 6;
    const int l = tid & 63;
    const int ll = l & 31;
    const int hi = l >> 5;
    const bool lo_half = (hi == 0);

    __shared__ alignas(16) unsigned char lds[65536];  // K[2][16KB] + V[2][16KB]

    const bf16_t* Qg = QKV;
    const bf16_t* Kg = QKV + 2048;
    const bf16_t* Vg = QKV + 4096;
    const size_t kvbase = (size_t)(sq * SEQLEN) * LDQ + h * 64;

    bf16x8 vr0, vr1;
    const int vk0 = l * 2;
    const int vd0 = w * 8;

    auto stageK = [&](int kt, int buf) {
#pragma unroll
        for (int c = 0; c < 2; ++c) {
            const int o = (w * 2 + c) * 1024 + l * 16;
            const int r = o >> 7;
            const int swb = (o & 127) ^ ((r & 7) << 4);
            const bf16_t* src = Kg + kvbase + (size_t)(kt * 128 + r) * LDQ + (swb >> 1);
            __builtin_amdgcn_global_load_lds(
                (const __attribute__((address_space(1))) void*)src,
                (__attribute__((address_space(3))) void*)(lds + buf * 16384 + (w * 2 + c) * 1024),
                16, 0, 0);
        }
    };
    auto loadV = [&](int kt) {
        const bf16_t* vp = Vg + kvbase + (size_t)(kt * 128 + vk0) * LDQ + vd0;
        vr0 = *reinterpret_cast<const bf16x8*>(vp);
        vr1 = *reinterpret_cast<const bf16x8*>(vp + LDQ);
    };
    auto writeV = [&](int buf) {
        u16x8 s0 = __builtin_bit_cast(u16x8, vr0);
        u16x8 s1 = __builtin_bit_cast(u16x8, vr1);
        unsigned char* vb = lds + 32768 + buf * 16384;
#pragma unroll
        for (int e = 0; e < 8; ++e) {
            const int d = vd0 + e;
            unsigned off = (unsigned)(d * 256 + vk0 * 2);
            off ^= ((unsigned)((d ^ (d >> 4)) & 15)) << 4;
            *reinterpret_cast<unsigned*>(vb + off) = (unsigned)s0[e] | ((unsigned)s1[e] << 16);
        }
    };

    const unsigned ksw = (unsigned)((l & 7) << 4);
    const unsigned kbase = (unsigned)(ll * 128 + hi * 16);

#pragma unroll 1
    for (int seg = 0; seg < 2; ++seg) {
        const int qt = pairIdx ? (seg ? 2 : 1) : (seg ? 3 : 0);

        const int q_glob = qt * 256 + w * 32 + ll;
        const bf16_t* qp = Qg + (size_t)(sq * SEQLEN + q_glob) * LDQ + h * 64 + hi * 8;
        bf16x8 qf[4];
#pragma unroll
        for (int dc = 0; dc < 4; ++dc)
            qf[dc] = *reinterpret_cast<const bf16x8*>(qp + dc * 16);

        const int nkt = 2 * qt + 2;
        const int q_wave_max = qt * 256 + w * 32 + 31;

        f32x16 oac[2] = {};
        float mrun = -3.0e38f, lsum = 0.f;

        stageK(0, 0);
        loadV(0);
        writeV(0);
        __syncthreads();

        int cur = 0;
        for (int kt = 0; kt < nkt; ++kt) {
            const bool notlast = (kt + 1 < nkt);
            if (notlast) { stageK(kt + 1, cur ^ 1); loadV(kt + 1); }

            if (kt * 128 <= q_wave_max) {
                const unsigned char* Kcur = lds + cur * 16384;
                const unsigned char* Vcur = lds + 32768 + cur * 16384;

                f32x16 st[4];
#pragma unroll
                for (int kh = 0; kh < 4; ++kh) {
                    f32x16 acc = {};
#pragma unroll
                    for (int dc = 0; dc < 4; ++dc) {
                        const unsigned off = (kbase + (unsigned)(kh * 4096 + dc * 32)) ^ ksw;
                        const bf16x8 ka = *reinterpret_cast<const bf16x8*>(Kcur + off);
                        acc = __builtin_amdgcn_mfma_f32_32x32x16_bf16(ka, qf[dc], acc, 0, 0, 0);
                    }
                    st[kh] = acc;
                }

                if (kt >= 2 * qt) {
#pragma unroll
                    for (int kh = 0; kh < 4; ++kh)
#pragma unroll
                        for (int r = 0; r < 16; ++r) {
                            const int kg = kt * 128 + kh * 32 + (r & 3) + 8 * (r >> 2) + 4 * hi;
                            if (kg > q_glob) st[kh][r] = -3.0e38f;
                        }
                }

                float tm = -3.0e38f;
#pragma unroll
                for (int kh = 0; kh < 4; ++kh)
#pragma unroll
                    for (int r = 0; r < 16; ++r) tm = fmaxf(tm, st[kh][r]);
                tm = fmaxf(tm, __shfl_xor(tm, 32));

                if (!__all(tm <= mrun + 8.0f)) {
                    const float mnew = fmaxf(mrun, tm);
                    const float rsc = EXP2F(mrun - mnew);
                    mrun = mnew;
                    lsum *= rsc;
#pragma unroll
                    for (int dh = 0; dh < 2; ++dh)
#pragma unroll
                        for (int r = 0; r < 16; ++r) oac[dh][r] *= rsc;
                }

                float ps = 0.f;
#pragma unroll
                for (int kh = 0; kh < 4; ++kh)
#pragma unroll
                    for (int r = 0; r < 16; ++r) {
                        const float p = EXP2F(st[kh][r] - mrun);
                        st[kh][r] = p;
                        ps += p;
                    }
                ps += __shfl_xor(ps, 32);
                lsum += ps;

                bf16x8 pf[8];
#pragma unroll
                for (int kh = 0; kh < 4; ++kh)
#pragma unroll
                    for (int hc = 0; hc < 2; ++hc) {
                        const int b0i = hc * 8;
                        unsigned a  = cvtpk_bf16(st[kh][b0i + 0], st[kh][b0i + 1]);
                        unsigned b  = cvtpk_bf16(st[kh][b0i + 4], st[kh][b0i + 5]);
                        unsigned a2 = cvtpk_bf16(st[kh][b0i + 2], st[kh][b0i + 3]);
                        unsigned b2 = cvtpk_bf16(st[kh][b0i + 6], st[kh][b0i + 7]);
                        plswap(a, b, lo_half);
                        plswap(a2, b2, lo_half);
                        u32x4 words = { a, a2, b, b2 };
                        pf[kh * 2 + hc] = __builtin_bit_cast(bf16x8, words);
                    }

#pragma unroll
                for (int dh = 0; dh < 2; ++dh) {
                    const int d = dh * 32 + ll;
                    const unsigned vsw = ((unsigned)((d ^ (d >> 4)) & 15)) << 4;
                    const unsigned vbb = (unsigned)(d * 256 + hi * 16);
#pragma unroll
                    for (int kc = 0; kc < 8; ++kc) {
                        const unsigned off = (vbb + (unsigned)(kc * 32)) ^ vsw;
                        const bf16x8 vfr = *reinterpret_cast<const bf16x8*>(Vcur + off);
                        oac[dh] = __builtin_amdgcn_mfma_f32_32x32x16_bf16(vfr, pf[kc], oac[dh], 0, 0, 0);
                    }
                }
            }

            if (notlast) writeV(cur ^ 1);
            __syncthreads();
            cur ^= 1;
        }

        const float inv = 1.0f / lsum;
        bf16_t* op = Og + (size_t)(sq * SEQLEN + q_glob) * E_DIM + h * 64;
#pragma unroll
        for (int dh = 0; dh < 2; ++dh)
#pragma unroll
            for (int rq = 0; rq < 4; ++rq) {
                const int d0 = dh * 32 + 8 * rq + 4 * hi;
                bf16x4 ov;
#pragma unroll
                for (int j = 0; j < 4; ++j)
                    ov[j] = (bf16_t)(oac[dh][rq * 4 + j] * inv);
                *reinterpret_cast<bf16x4*>(op + d0) = ov;
            }
    }
}

// ---------------------------------------------------------------------------
extern "C" void kernel_launch(void* const* d_in, const int* in_sizes, int n_in,
                              void* d_out, int out_size, void* d_ws, size_t ws_size,
                              hipStream_t stream) {
    const float* hid = (const float*)d_in[0];
    const float* Wq  = (const float*)d_in[1];
    const float* bq  = (const float*)d_in[2];
    const float* Wk  = (const float*)d_in[3];
    const float* bk  = (const float*)d_in[4];
    const float* Wv  = (const float*)d_in[5];
    const float* bv  = (const float*)d_in[6];
    const float* Wo  = (const float*)d_in[7];
    const float* bo  = (const float*)d_in[8];
    float* out = (float*)d_out;

    const size_t TE = (size_t)T_TOK * E_DIM;
    const size_t EE = (size_t)E_DIM * E_DIM;

    bf16_t* ws   = (bf16_t*)d_ws;
    bf16_t* hidB = ws;                 // later reused as attention output
    bf16_t* qkvB = ws + TE;            // [8192][6144]
    bf16_t* Wcat = qkvB + 3 * TE;      // [6144][2048] = Wq|Wk|Wv rows
    bf16_t* WoB  = Wcat + 3 * EE;

    cvt_all<<<4096, 256, 0, stream>>>(hid, Wq, Wk, Wv, Wo, hidB, Wcat, WoB);

    // Q pre-scaled by D^-0.5 * log2(e): attention runs in exp2 domain.
    const float QSCALE = 0.125f * 1.4426950408889634f;

    gemm256f<true><<<dim3((T_TOK / 256) * (LDQ / 256)), 512, 0, stream>>>(
        hidB, Wcat, bq, bk, bv, qkvB, T_TOK, LDQ, QSCALE, 2048);

    attn_fwd3<<<dim3(512), 512, 0, stream>>>(qkvB, hidB);

    gemm256f<false><<<dim3((T_TOK / 256) * (E_DIM / 256)), 512, 0, stream>>>(
        hidB, WoB, bo, bo, bo, out, T_TOK, E_DIM, 1.0f, 0);
}